// Round 2
// baseline (666.480 us; speedup 1.0000x reference)
//
#include <hip/hip_runtime.h>
#include <hip/hip_bf16.h>

#define BB 8
#define CC 64
#define LL 4096
#define DD 128
#define NN 16
#define EPS 1e-5f
#define NCH 128
#define CLEN 32

__device__ __forceinline__ float silu_f(float v) {
    return v / (1.f + __expf(-v));
}
__device__ __forceinline__ float softplus_f(float t) {
    return fmaxf(t, 0.f) + __logf(1.f + __expf(-fabsf(t)));
}

// ---------------- K0: residual 1x1 conv + BN -> d_out ----------------
__global__ __launch_bounds__(256) void k_res(const float* __restrict__ x,
                                             const float* __restrict__ rw,
                                             const float* __restrict__ rbn,
                                             float* __restrict__ out) {
    int b = blockIdx.x >> 4;
    int s = ((blockIdx.x & 15) << 8) + threadIdx.x;
    const float* xb = x + (size_t)b * CC * LL;
    float xv[64];
#pragma unroll
    for (int ic = 0; ic < 64; ic++) xv[ic] = xb[ic * LL + s];
    for (int oc = 0; oc < 64; oc++) {
        float acc = 0.f;
#pragma unroll
        for (int ic = 0; ic < 64; ic++) acc = fmaf(xv[ic], rw[oc * 64 + ic], acc);
        float g = rbn[oc], be = rbn[64 + oc], m = rbn[128 + oc], v = rbn[192 + oc];
        float sc = g * rsqrtf(v + EPS);
        float sh = be - m * sc;
        out[((size_t)b * 64 + oc) * LL + s] = fmaf(acc, sc, sh);
    }
}

// ---------------- K1: in_proj GEMM -> xm_raw (B,D,L), zg (B,L,D) ----------------
__global__ __launch_bounds__(256) void k_inproj(const float* __restrict__ x,
                                                const float* __restrict__ w,
                                                float* __restrict__ xm_raw,
                                                float* __restrict__ zg) {
    int b = blockIdx.x >> 6;
    int l0 = (blockIdx.x & 63) << 6;
    int lane = threadIdx.x & 63;
    int jg = threadIdx.x >> 6;
    int jb = __builtin_amdgcn_readfirstlane(jg);
    int l = l0 + lane;
    __shared__ float z_t[128][65];
    const float* xb = x + (size_t)b * CC * LL;
    float xv[64];
#pragma unroll
    for (int c = 0; c < 64; c++) xv[c] = xb[c * LL + l];
    const float* wrow = w + jb * 64 * 64;
    if (jb < 2) {
        float* ob = xm_raw + ((size_t)b * DD + jb * 64) * LL + l0;
        for (int jj = 0; jj < 64; jj++) {
            float acc = 0.f;
#pragma unroll
            for (int c = 0; c < 64; c++) acc = fmaf(xv[c], wrow[jj * 64 + c], acc);
            ob[(size_t)jj * LL + lane] = acc;
        }
    } else {
        int zd0 = (jb - 2) * 64;
        for (int jj = 0; jj < 64; jj++) {
            float acc = 0.f;
#pragma unroll
            for (int c = 0; c < 64; c++) acc = fmaf(xv[c], wrow[jj * 64 + c], acc);
            z_t[zd0 + jj][lane] = acc;
        }
    }
    __syncthreads();
    int d = threadIdx.x & 127, lsub = threadIdx.x >> 7;
    float* zb = zg + ((size_t)b * LL + l0) * DD;
    for (int p = 0; p < 32; p++) {
        int ll = p * 2 + lsub;
        zb[(size_t)ll * DD + d] = z_t[d][ll];
    }
}

// ---------------- K1b: causal depthwise conv1d (k=4) + SiLU -> xmg (B,L,D) ----------------
__global__ __launch_bounds__(256) void k_conv1d(const float* __restrict__ xm_raw,
                                                const float* __restrict__ cw,
                                                const float* __restrict__ cb,
                                                float* __restrict__ xmg) {
    int b = blockIdx.x >> 6;
    int l0 = (blockIdx.x & 63) << 6;
    __shared__ float s[128][69];
    for (int idx = threadIdx.x; idx < 128 * 67; idx += 256) {
        int row = idx / 67, col = idx % 67;
        int l = l0 - 3 + col;
        s[row][col] = (l >= 0) ? xm_raw[((size_t)b * DD + row) * LL + l] : 0.f;
    }
    __syncthreads();
    int d = threadIdx.x & 127, lsub = threadIdx.x >> 7;
    float w0 = cw[d * 4], w1 = cw[d * 4 + 1], w2 = cw[d * 4 + 2], w3 = cw[d * 4 + 3];
    float bb = cb[d];
    float* ob = xmg + ((size_t)b * LL + l0) * DD;
#pragma unroll 4
    for (int i = 0; i < 32; i++) {
        int ll = i * 2 + lsub;
        float v = bb + w0 * s[d][ll] + w1 * s[d][ll + 1] + w2 * s[d][ll + 2] + w3 * s[d][ll + 3];
        ob[(size_t)ll * DD + d] = silu_f(v);
    }
}

// ---------------- K2: x_proj -> Bc2 (B,L,16), Cc2 (B,L,16), dtp (B,L,4) ----------------
__global__ __launch_bounds__(256) void k_xproj_bc(const float* __restrict__ xmg,
                                                  const float* __restrict__ xw,
                                                  float* __restrict__ Bc2,
                                                  float* __restrict__ Cc2,
                                                  float* __restrict__ dtpO) {
    int bl = blockIdx.x * 256 + threadIdx.x;
    const float* xr = xmg + (size_t)bl * DD;
    float acc[36];
#pragma unroll
    for (int j = 0; j < 36; j++) acc[j] = 0.f;
    for (int c8 = 0; c8 < 8; c8++) {
        float4 v0 = *(const float4*)(xr + c8 * 16 + 0);
        float4 v1 = *(const float4*)(xr + c8 * 16 + 4);
        float4 v2 = *(const float4*)(xr + c8 * 16 + 8);
        float4 v3 = *(const float4*)(xr + c8 * 16 + 12);
        float xv[16] = {v0.x, v0.y, v0.z, v0.w, v1.x, v1.y, v1.z, v1.w,
                        v2.x, v2.y, v2.z, v2.w, v3.x, v3.y, v3.z, v3.w};
#pragma unroll
        for (int jj = 0; jj < 36; jj++) {
            const float* wr = xw + jj * DD + c8 * 16;
            float a = acc[jj];
#pragma unroll
            for (int j = 0; j < 16; j++) a = fmaf(xv[j], wr[j], a);
            acc[jj] = a;
        }
    }
    *(float4*)(dtpO + (size_t)bl * 4) = make_float4(acc[0], acc[1], acc[2], acc[3]);
    float* Bp = Bc2 + (size_t)bl * 16;
    float* Cp = Cc2 + (size_t)bl * 16;
#pragma unroll
    for (int q = 0; q < 4; q++) {
        *(float4*)(Bp + q * 4) = make_float4(acc[4 + q * 4], acc[5 + q * 4], acc[6 + q * 4], acc[7 + q * 4]);
        *(float4*)(Cp + q * 4) = make_float4(acc[20 + q * 4], acc[21 + q * 4], acc[22 + q * 4], acc[23 + q * 4]);
    }
}

// ---------------- Scan pass 1: per-chunk local scan, h[16] in registers ----------------
__global__ __launch_bounds__(64) void k_s1(const float* __restrict__ xmg,
                                           const float* __restrict__ Bc2,
                                           const float* __restrict__ dtpI,
                                           const float* __restrict__ dtw,
                                           const float* __restrict__ dtb,
                                           const float* __restrict__ A_log,
                                           float* __restrict__ chH,
                                           float* __restrict__ chP) {
    int g = blockIdx.x;
    int ck = g & (NCH - 1);
    int dh = (g >> 7) & 1;
    int b = g >> 8;
    int lane = threadIdx.x;
    int d = dh * 64 + lane;
    float a2[16];
#pragma unroll
    for (int j = 0; j < 4; j++) {
        float4 v = *(const float4*)(A_log + d * 16 + j * 4);
        a2[j * 4 + 0] = -__expf(v.x) * 1.4426950408889634f;
        a2[j * 4 + 1] = -__expf(v.y) * 1.4426950408889634f;
        a2[j * 4 + 2] = -__expf(v.z) * 1.4426950408889634f;
        a2[j * 4 + 3] = -__expf(v.w) * 1.4426950408889634f;
    }
    float4 dw = *(const float4*)(dtw + d * 4);
    float dtbd = dtb[d];
    float h[16];
#pragma unroll
    for (int n = 0; n < 16; n++) h[n] = 0.f;
    float sdt = 0.f;
    size_t bl0 = (size_t)b * LL + ck * CLEN;
    const float* xmp = xmg + bl0 * DD + d;
    const float* Bp = Bc2 + bl0 * 16;
    const float* dpp = dtpI + bl0 * 4;
#pragma unroll 2
    for (int t = 0; t < CLEN; t++) {
        float xmv = xmp[(size_t)t * DD];
        float4 q = *(const float4*)(dpp + t * 4);
        float tp = dtbd + q.x * dw.x + q.y * dw.y + q.z * dw.z + q.w * dw.w;
        float dtv = softplus_f(tp);
        float dx = dtv * xmv;
        float4 B0 = *(const float4*)(Bp + t * 16);
        float4 B1 = *(const float4*)(Bp + t * 16 + 4);
        float4 B2 = *(const float4*)(Bp + t * 16 + 8);
        float4 B3 = *(const float4*)(Bp + t * 16 + 12);
        float Bv[16] = {B0.x, B0.y, B0.z, B0.w, B1.x, B1.y, B1.z, B1.w,
                        B2.x, B2.y, B2.z, B2.w, B3.x, B3.y, B3.z, B3.w};
#pragma unroll
        for (int n = 0; n < 16; n++) {
            float dA = exp2f(dtv * a2[n]);
            h[n] = fmaf(dA, h[n], dx * Bv[n]);
        }
        sdt += dtv;
    }
    size_t cbase = ((size_t)((b * 2 + dh) * NCH + ck)) * 1024 + lane * 16;
#pragma unroll
    for (int j = 0; j < 4; j++) {
        *(float4*)(chH + cbase + j * 4) = make_float4(h[j * 4], h[j * 4 + 1], h[j * 4 + 2], h[j * 4 + 3]);
        *(float4*)(chP + cbase + j * 4) = make_float4(exp2f(a2[j * 4] * sdt), exp2f(a2[j * 4 + 1] * sdt),
                                                      exp2f(a2[j * 4 + 2] * sdt), exp2f(a2[j * 4 + 3] * sdt));
    }
}

// ---------------- Scan pass 2: compose chunks; write prefix h_init in place into chH ----------------
__global__ __launch_bounds__(256) void k_s2(float* __restrict__ chH,
                                            const float* __restrict__ chP) {
    int T = blockIdx.x * 256 + threadIdx.x;   // 0..1023
    int row = T >> 6;
    int lane = T & 63;
    float H[16];
#pragma unroll
    for (int n = 0; n < 16; n++) H[n] = 0.f;
    size_t base = (size_t)row * NCH * 1024 + lane * 16;
    for (int ck = 0; ck < NCH; ck++) {
        size_t a = base + (size_t)ck * 1024;
        float4 h0 = *(const float4*)(chH + a);
        float4 h1 = *(const float4*)(chH + a + 4);
        float4 h2 = *(const float4*)(chH + a + 8);
        float4 h3 = *(const float4*)(chH + a + 12);
        float4 p0 = *(const float4*)(chP + a);
        float4 p1 = *(const float4*)(chP + a + 4);
        float4 p2 = *(const float4*)(chP + a + 8);
        float4 p3 = *(const float4*)(chP + a + 12);
        *(float4*)(chH + a) = make_float4(H[0], H[1], H[2], H[3]);
        *(float4*)(chH + a + 4) = make_float4(H[4], H[5], H[6], H[7]);
        *(float4*)(chH + a + 8) = make_float4(H[8], H[9], H[10], H[11]);
        *(float4*)(chH + a + 12) = make_float4(H[12], H[13], H[14], H[15]);
        float hc[16] = {h0.x, h0.y, h0.z, h0.w, h1.x, h1.y, h1.z, h1.w,
                        h2.x, h2.y, h2.z, h2.w, h3.x, h3.y, h3.z, h3.w};
        float pc[16] = {p0.x, p0.y, p0.z, p0.w, p1.x, p1.y, p1.z, p1.w,
                        p2.x, p2.y, p2.z, p2.w, p3.x, p3.y, p3.z, p3.w};
#pragma unroll
        for (int n = 0; n < 16; n++) H[n] = fmaf(pc[n], H[n], hc[n]);
    }
}

// ---------------- Scan pass 3: re-scan from h_init, emit gated y (B,L,D) ----------------
__global__ __launch_bounds__(64) void k_s3(const float* __restrict__ xmg,
                                           const float* __restrict__ zg,
                                           const float* __restrict__ Bc2,
                                           const float* __restrict__ Cc2,
                                           const float* __restrict__ dtpI,
                                           const float* __restrict__ dtw,
                                           const float* __restrict__ dtb,
                                           const float* __restrict__ A_log,
                                           const float* __restrict__ Dpp,
                                           const float* __restrict__ hinit,
                                           float* __restrict__ Y) {
    int g = blockIdx.x;
    int ck = g & (NCH - 1);
    int dh = (g >> 7) & 1;
    int b = g >> 8;
    int lane = threadIdx.x;
    int d = dh * 64 + lane;
    float a2[16];
#pragma unroll
    for (int j = 0; j < 4; j++) {
        float4 v = *(const float4*)(A_log + d * 16 + j * 4);
        a2[j * 4 + 0] = -__expf(v.x) * 1.4426950408889634f;
        a2[j * 4 + 1] = -__expf(v.y) * 1.4426950408889634f;
        a2[j * 4 + 2] = -__expf(v.z) * 1.4426950408889634f;
        a2[j * 4 + 3] = -__expf(v.w) * 1.4426950408889634f;
    }
    float4 dw = *(const float4*)(dtw + d * 4);
    float dtbd = dtb[d];
    float Dpd = Dpp[d];
    size_t cbase = ((size_t)((b * 2 + dh) * NCH + ck)) * 1024 + lane * 16;
    float h[16];
#pragma unroll
    for (int j = 0; j < 4; j++) {
        float4 v = *(const float4*)(hinit + cbase + j * 4);
        h[j * 4 + 0] = v.x; h[j * 4 + 1] = v.y; h[j * 4 + 2] = v.z; h[j * 4 + 3] = v.w;
    }
    size_t bl0 = (size_t)b * LL + ck * CLEN;
    const float* xmp = xmg + bl0 * DD + d;
    const float* zp = zg + bl0 * DD + d;
    const float* Bp = Bc2 + bl0 * 16;
    const float* Cp = Cc2 + bl0 * 16;
    const float* dpp = dtpI + bl0 * 4;
    float* Yp = Y + bl0 * DD + d;
#pragma unroll 2
    for (int t = 0; t < CLEN; t++) {
        float xmv = xmp[(size_t)t * DD];
        float zv = zp[(size_t)t * DD];
        float4 q = *(const float4*)(dpp + t * 4);
        float tp = dtbd + q.x * dw.x + q.y * dw.y + q.z * dw.z + q.w * dw.w;
        float dtv = softplus_f(tp);
        float dx = dtv * xmv;
        float4 B0 = *(const float4*)(Bp + t * 16);
        float4 B1 = *(const float4*)(Bp + t * 16 + 4);
        float4 B2 = *(const float4*)(Bp + t * 16 + 8);
        float4 B3 = *(const float4*)(Bp + t * 16 + 12);
        float4 C0 = *(const float4*)(Cp + t * 16);
        float4 C1 = *(const float4*)(Cp + t * 16 + 4);
        float4 C2 = *(const float4*)(Cp + t * 16 + 8);
        float4 C3 = *(const float4*)(Cp + t * 16 + 12);
        float Bv[16] = {B0.x, B0.y, B0.z, B0.w, B1.x, B1.y, B1.z, B1.w,
                        B2.x, B2.y, B2.z, B2.w, B3.x, B3.y, B3.z, B3.w};
        float Cv[16] = {C0.x, C0.y, C0.z, C0.w, C1.x, C1.y, C1.z, C1.w,
                        C2.x, C2.y, C2.z, C2.w, C3.x, C3.y, C3.z, C3.w};
        float y0 = 0.f, y1 = 0.f, y2 = 0.f, y3 = 0.f;
#pragma unroll
        for (int n = 0; n < 16; n += 4) {
            float dA0 = exp2f(dtv * a2[n]);
            float dA1 = exp2f(dtv * a2[n + 1]);
            float dA2 = exp2f(dtv * a2[n + 2]);
            float dA3 = exp2f(dtv * a2[n + 3]);
            h[n] = fmaf(dA0, h[n], dx * Bv[n]);
            h[n + 1] = fmaf(dA1, h[n + 1], dx * Bv[n + 1]);
            h[n + 2] = fmaf(dA2, h[n + 2], dx * Bv[n + 2]);
            h[n + 3] = fmaf(dA3, h[n + 3], dx * Bv[n + 3]);
            y0 = fmaf(h[n], Cv[n], y0);
            y1 = fmaf(h[n + 1], Cv[n + 1], y1);
            y2 = fmaf(h[n + 2], Cv[n + 2], y2);
            y3 = fmaf(h[n + 3], Cv[n + 3], y3);
        }
        float yv = (y0 + y1) + (y2 + y3);
        yv = fmaf(xmv, Dpd, yv);
        Yp[(size_t)t * DD] = yv * silu_f(zv);
    }
}

// ---------------- K4: out_proj + PReLU -> out_tok (B,64,L) ----------------
__global__ __launch_bounds__(256) void k_outproj(const float* __restrict__ Y,
                                                 const float* __restrict__ wo,
                                                 const float* __restrict__ pre,
                                                 float* __restrict__ out_tok) {
    int blk = blockIdx.x;
    int half = blk & 1;
    int bl = (blk >> 1) * 256 + threadIdx.x;
    int oc0 = half * 32;
    const float* yr = Y + (size_t)bl * DD;
    float acc[32];
#pragma unroll
    for (int o = 0; o < 32; o++) acc[o] = 0.f;
    for (int c8 = 0; c8 < 8; c8++) {
        float4 v0 = *(const float4*)(yr + c8 * 16 + 0);
        float4 v1 = *(const float4*)(yr + c8 * 16 + 4);
        float4 v2 = *(const float4*)(yr + c8 * 16 + 8);
        float4 v3 = *(const float4*)(yr + c8 * 16 + 12);
        float xv[16] = {v0.x, v0.y, v0.z, v0.w, v1.x, v1.y, v1.z, v1.w,
                        v2.x, v2.y, v2.z, v2.w, v3.x, v3.y, v3.z, v3.w};
#pragma unroll
        for (int o = 0; o < 32; o++) {
            const float* wr = wo + (size_t)(oc0 + o) * DD + c8 * 16;
            float a = acc[o];
#pragma unroll
            for (int j = 0; j < 16; j++) a = fmaf(xv[j], wr[j], a);
            acc[o] = a;
        }
    }
    float pa = pre[0];
    int b = bl >> 12, l = bl & 4095;
    for (int o = 0; o < 32; o++) {
        float v = acc[o];
        v = v >= 0.f ? v : pa * v;
        out_tok[((size_t)b * 64 + oc0 + o) * LL + l] = v;
    }
}

// ---------------- K5/K6: 3x3 conv + BN + PReLU (+residual add) ----------------
template <bool TR, bool ADD>
__global__ __launch_bounds__(256) void k_conv3(const float* __restrict__ inp,
                                               const float* __restrict__ w,
                                               const float* __restrict__ bnp,
                                               const float* __restrict__ pre,
                                               const float* __restrict__ addp,
                                               float* __restrict__ outp) {
    int bid = blockIdx.x;
    int b = bid >> 6;
    int tile = bid & 63;
    int i0 = (tile >> 3) * 8;
    int j0 = (tile & 7) * 8;
    int pos = threadIdx.x & 63;
    int ocg = threadIdx.x >> 6;
    int ti = pos >> 3, tj = pos & 7;
    __shared__ float in_t[64][10][10];
    const float* ib = inp + (size_t)b * 64 * LL;
    for (int idx = threadIdx.x; idx < 6400; idx += 256) {
        int ic, pp, qq;
        if (TR) {
            pp = idx % 10;
            int rem = idx / 10;
            qq = rem % 10;
            ic = rem / 10;
        } else {
            qq = idx % 10;
            int rem = idx / 10;
            pp = rem % 10;
            ic = rem / 10;
        }
        int p = i0 - 1 + pp, qv = j0 - 1 + qq;
        float v = 0.f;
        if (p >= 0 && p < 64 && qv >= 0 && qv < 64)
            v = TR ? ib[ic * LL + qv * 64 + p] : ib[ic * LL + p * 64 + qv];
        in_t[ic][pp][qq] = v;
    }
    __syncthreads();
    float acc[16];
#pragma unroll
    for (int o = 0; o < 16; o++) acc[o] = 0.f;
    int oc0 = __builtin_amdgcn_readfirstlane(ocg) * 16;
    for (int ic = 0; ic < 64; ic++) {
        float iv[3][3];
#pragma unroll
        for (int di = 0; di < 3; di++)
#pragma unroll
            for (int dj = 0; dj < 3; dj++) iv[di][dj] = in_t[ic][ti + di][tj + dj];
#pragma unroll
        for (int o = 0; o < 16; o++) {
            const float* wr = w + ((size_t)(oc0 + o) * 64 + ic) * 9;
            float a = acc[o];
            a = fmaf(iv[0][0], wr[0], a);
            a = fmaf(iv[0][1], wr[1], a);
            a = fmaf(iv[0][2], wr[2], a);
            a = fmaf(iv[1][0], wr[3], a);
            a = fmaf(iv[1][1], wr[4], a);
            a = fmaf(iv[1][2], wr[5], a);
            a = fmaf(iv[2][0], wr[6], a);
            a = fmaf(iv[2][1], wr[7], a);
            a = fmaf(iv[2][2], wr[8], a);
            acc[o] = a;
        }
    }
    float pa = pre[0];
#pragma unroll
    for (int o = 0; o < 16; o++) {
        int oc = oc0 + o;
        float g = bnp[oc], be = bnp[64 + oc], m = bnp[128 + oc], vv = bnp[192 + oc];
        float sc = g * rsqrtf(vv + EPS);
        float sh = be - m * sc;
        float v = fmaf(acc[o], sc, sh);
        v = v >= 0.f ? v : pa * v;
        size_t addr = ((size_t)b * 64 + oc) * LL + (i0 + ti) * 64 + (j0 + tj);
        if (ADD) v += addp[addr];
        outp[addr] = v;
    }
}

extern "C" void kernel_launch(void* const* d_in, const int* in_sizes, int n_in,
                              void* d_out, int out_size, void* d_ws, size_t ws_size,
                              hipStream_t stream) {
    const float* x = (const float*)d_in[0];
    const float* in_proj_w = (const float*)d_in[1];
    const float* conv1d_w = (const float*)d_in[2];
    const float* conv1d_b = (const float*)d_in[3];
    const float* x_proj_w = (const float*)d_in[4];
    const float* dt_proj_w = (const float*)d_in[5];
    const float* dt_proj_b = (const float*)d_in[6];
    const float* A_log = (const float*)d_in[7];
    const float* Dp = (const float*)d_in[8];
    const float* out_proj_w = (const float*)d_in[9];
    const float* prelu_ssm = (const float*)d_in[10];
    const float* res_w = (const float*)d_in[11];
    const float* res_bn = (const float*)d_in[12];
    const float* conv1_w = (const float*)d_in[13];
    const float* bn1 = (const float*)d_in[14];
    const float* prelu1 = (const float*)d_in[15];
    const float* conv2_w = (const float*)d_in[16];
    const float* bn2 = (const float*)d_in[17];
    const float* prelu2 = (const float*)d_in[18];
    float* out = (float*)d_out;
    float* ws = (float*)d_ws;

    const size_t S = (size_t)BB * LL * DD;        // 4,194,304
    const size_t HALF = S / 2;                    // 2,097,152
    float* xm_raw = ws;                           // [0,S) dead after conv1d
    float* chH = ws;                              // reuse  [0,HALF)
    float* chP = ws + HALF;                       //        [HALF,S)
    float* xmg = ws + S;                          // (B,L,D); reused as out_tok after s3
    float* zg = ws + 2 * S;                       // (B,L,D); reused as img2 after s3
    float* Yb = ws + 3 * S;                       // (B,L,D)
    float* Bc2 = ws + 4 * S;                      // B*L*16
    float* Cc2 = Bc2 + (size_t)BB * LL * 16;
    float* dtp = Cc2 + (size_t)BB * LL * 16;      // B*L*4
    float* out_tok = xmg;
    float* img2 = zg;

    k_res<<<dim3(128), dim3(256), 0, stream>>>(x, res_w, res_bn, out);
    k_inproj<<<dim3(512), dim3(256), 0, stream>>>(x, in_proj_w, xm_raw, zg);
    k_conv1d<<<dim3(512), dim3(256), 0, stream>>>(xm_raw, conv1d_w, conv1d_b, xmg);
    k_xproj_bc<<<dim3(128), dim3(256), 0, stream>>>(xmg, x_proj_w, Bc2, Cc2, dtp);
    k_s1<<<dim3(BB * 2 * NCH), dim3(64), 0, stream>>>(xmg, Bc2, dtp, dt_proj_w, dt_proj_b, A_log, chH, chP);
    k_s2<<<dim3(4), dim3(256), 0, stream>>>(chH, chP);
    k_s3<<<dim3(BB * 2 * NCH), dim3(64), 0, stream>>>(xmg, zg, Bc2, Cc2, dtp, dt_proj_w, dt_proj_b,
                                                      A_log, Dp, chH, Yb);
    k_outproj<<<dim3(256), dim3(256), 0, stream>>>(Yb, out_proj_w, prelu_ssm, out_tok);
    k_conv3<true, false><<<dim3(512), dim3(256), 0, stream>>>(out_tok, conv1_w, bn1, prelu1, nullptr, img2);
    k_conv3<false, true><<<dim3(512), dim3(256), 0, stream>>>(img2, conv2_w, bn2, prelu2, out, out);
}

// Round 3
// 526.500 us; speedup vs baseline: 1.2659x; 1.2659x over previous
//
#include <hip/hip_runtime.h>
#include <hip/hip_bf16.h>

#define BB 8
#define CC 64
#define LL 4096
#define DD 128
#define NN 16
#define EPS 1e-5f
#define NCH 128
#define CLEN 32

__device__ __forceinline__ float silu_f(float v) {
    return v / (1.f + __expf(-v));
}
__device__ __forceinline__ float softplus_f(float t) {
    return fmaxf(t, 0.f) + __logf(1.f + __expf(-fabsf(t)));
}

// ---------------- K0: residual 1x1 conv + BN -> d_out ----------------
__global__ __launch_bounds__(256) void k_res(const float* __restrict__ x,
                                             const float* __restrict__ rw,
                                             const float* __restrict__ rbn,
                                             float* __restrict__ out) {
    int b = blockIdx.x >> 4;
    int s = ((blockIdx.x & 15) << 8) + threadIdx.x;
    const float* xb = x + (size_t)b * CC * LL;
    float xv[64];
#pragma unroll
    for (int ic = 0; ic < 64; ic++) xv[ic] = xb[ic * LL + s];
    for (int oc = 0; oc < 64; oc++) {
        float acc = 0.f;
#pragma unroll
        for (int ic = 0; ic < 64; ic++) acc = fmaf(xv[ic], rw[oc * 64 + ic], acc);
        float g = rbn[oc], be = rbn[64 + oc], m = rbn[128 + oc], v = rbn[192 + oc];
        float sc = g * rsqrtf(v + EPS);
        float sh = be - m * sc;
        out[((size_t)b * 64 + oc) * LL + s] = fmaf(acc, sc, sh);
    }
}

// ---------------- K1: in_proj GEMM -> xm_raw (B,D,L), zg (B,L,D) ----------------
__global__ __launch_bounds__(256) void k_inproj(const float* __restrict__ x,
                                                const float* __restrict__ w,
                                                float* __restrict__ xm_raw,
                                                float* __restrict__ zg) {
    int b = blockIdx.x >> 6;
    int l0 = (blockIdx.x & 63) << 6;
    int lane = threadIdx.x & 63;
    int jg = threadIdx.x >> 6;
    int jb = __builtin_amdgcn_readfirstlane(jg);
    int l = l0 + lane;
    __shared__ float z_t[128][65];
    const float* xb = x + (size_t)b * CC * LL;
    float xv[64];
#pragma unroll
    for (int c = 0; c < 64; c++) xv[c] = xb[c * LL + l];
    const float* wrow = w + jb * 64 * 64;
    if (jb < 2) {
        float* ob = xm_raw + ((size_t)b * DD + jb * 64) * LL + l0;
        for (int jj = 0; jj < 64; jj++) {
            float acc = 0.f;
#pragma unroll
            for (int c = 0; c < 64; c++) acc = fmaf(xv[c], wrow[jj * 64 + c], acc);
            ob[(size_t)jj * LL + lane] = acc;
        }
    } else {
        int zd0 = (jb - 2) * 64;
        for (int jj = 0; jj < 64; jj++) {
            float acc = 0.f;
#pragma unroll
            for (int c = 0; c < 64; c++) acc = fmaf(xv[c], wrow[jj * 64 + c], acc);
            z_t[zd0 + jj][lane] = acc;
        }
    }
    __syncthreads();
    int d = threadIdx.x & 127, lsub = threadIdx.x >> 7;
    float* zb = zg + ((size_t)b * LL + l0) * DD;
    for (int p = 0; p < 32; p++) {
        int ll = p * 2 + lsub;
        zb[(size_t)ll * DD + d] = z_t[d][ll];
    }
}

// ---------------- K1b: causal depthwise conv1d (k=4) + SiLU -> xmg (B,L,D) ----------------
__global__ __launch_bounds__(256) void k_conv1d(const float* __restrict__ xm_raw,
                                                const float* __restrict__ cw,
                                                const float* __restrict__ cb,
                                                float* __restrict__ xmg) {
    int b = blockIdx.x >> 6;
    int l0 = (blockIdx.x & 63) << 6;
    __shared__ float s[128][69];
    for (int idx = threadIdx.x; idx < 128 * 67; idx += 256) {
        int row = idx / 67, col = idx % 67;
        int l = l0 - 3 + col;
        s[row][col] = (l >= 0) ? xm_raw[((size_t)b * DD + row) * LL + l] : 0.f;
    }
    __syncthreads();
    int d = threadIdx.x & 127, lsub = threadIdx.x >> 7;
    float w0 = cw[d * 4], w1 = cw[d * 4 + 1], w2 = cw[d * 4 + 2], w3 = cw[d * 4 + 3];
    float bb = cb[d];
    float* ob = xmg + ((size_t)b * LL + l0) * DD;
#pragma unroll 4
    for (int i = 0; i < 32; i++) {
        int ll = i * 2 + lsub;
        float v = bb + w0 * s[d][ll] + w1 * s[d][ll + 1] + w2 * s[d][ll + 2] + w3 * s[d][ll + 3];
        ob[(size_t)ll * DD + d] = silu_f(v);
    }
}

// ---------------- K2: x_proj -> Bc2 (B,L,16), Cc2 (B,L,16), dtp (B,L,4) ----------------
__global__ __launch_bounds__(256) void k_xproj_bc(const float* __restrict__ xmg,
                                                  const float* __restrict__ xw,
                                                  float* __restrict__ Bc2,
                                                  float* __restrict__ Cc2,
                                                  float* __restrict__ dtpO) {
    int bl = blockIdx.x * 256 + threadIdx.x;
    const float* xr = xmg + (size_t)bl * DD;
    float acc[36];
#pragma unroll
    for (int j = 0; j < 36; j++) acc[j] = 0.f;
    for (int c8 = 0; c8 < 8; c8++) {
        float4 v0 = *(const float4*)(xr + c8 * 16 + 0);
        float4 v1 = *(const float4*)(xr + c8 * 16 + 4);
        float4 v2 = *(const float4*)(xr + c8 * 16 + 8);
        float4 v3 = *(const float4*)(xr + c8 * 16 + 12);
        float xv[16] = {v0.x, v0.y, v0.z, v0.w, v1.x, v1.y, v1.z, v1.w,
                        v2.x, v2.y, v2.z, v2.w, v3.x, v3.y, v3.z, v3.w};
#pragma unroll
        for (int jj = 0; jj < 36; jj++) {
            const float* wr = xw + jj * DD + c8 * 16;
            float a = acc[jj];
#pragma unroll
            for (int j = 0; j < 16; j++) a = fmaf(xv[j], wr[j], a);
            acc[jj] = a;
        }
    }
    *(float4*)(dtpO + (size_t)bl * 4) = make_float4(acc[0], acc[1], acc[2], acc[3]);
    float* Bp = Bc2 + (size_t)bl * 16;
    float* Cp = Cc2 + (size_t)bl * 16;
#pragma unroll
    for (int q = 0; q < 4; q++) {
        *(float4*)(Bp + q * 4) = make_float4(acc[4 + q * 4], acc[5 + q * 4], acc[6 + q * 4], acc[7 + q * 4]);
        *(float4*)(Cp + q * 4) = make_float4(acc[20 + q * 4], acc[21 + q * 4], acc[22 + q * 4], acc[23 + q * 4]);
    }
}

// ---------------- Scan pass 1: per-chunk local scan, h[16] in registers ----------------
__global__ __launch_bounds__(64) void k_s1(const float* __restrict__ xmg,
                                           const float* __restrict__ Bc2,
                                           const float* __restrict__ dtpI,
                                           const float* __restrict__ dtw,
                                           const float* __restrict__ dtb,
                                           const float* __restrict__ A_log,
                                           float* __restrict__ chH,
                                           float* __restrict__ chP) {
    int g = blockIdx.x;
    int ck = g & (NCH - 1);
    int dh = (g >> 7) & 1;
    int b = g >> 8;
    int lane = threadIdx.x;
    int d = dh * 64 + lane;
    float a2[16];
#pragma unroll
    for (int j = 0; j < 4; j++) {
        float4 v = *(const float4*)(A_log + d * 16 + j * 4);
        a2[j * 4 + 0] = -__expf(v.x) * 1.4426950408889634f;
        a2[j * 4 + 1] = -__expf(v.y) * 1.4426950408889634f;
        a2[j * 4 + 2] = -__expf(v.z) * 1.4426950408889634f;
        a2[j * 4 + 3] = -__expf(v.w) * 1.4426950408889634f;
    }
    float4 dw = *(const float4*)(dtw + d * 4);
    float dtbd = dtb[d];
    float h[16];
#pragma unroll
    for (int n = 0; n < 16; n++) h[n] = 0.f;
    float sdt = 0.f;
    size_t bl0 = (size_t)b * LL + ck * CLEN;
    const float* xmp = xmg + bl0 * DD + d;
    const float* Bp = Bc2 + bl0 * 16;
    const float* dpp = dtpI + bl0 * 4;
#pragma unroll 2
    for (int t = 0; t < CLEN; t++) {
        float xmv = xmp[(size_t)t * DD];
        float4 q = *(const float4*)(dpp + t * 4);
        float tp = dtbd + q.x * dw.x + q.y * dw.y + q.z * dw.z + q.w * dw.w;
        float dtv = softplus_f(tp);
        float dx = dtv * xmv;
        float4 B0 = *(const float4*)(Bp + t * 16);
        float4 B1 = *(const float4*)(Bp + t * 16 + 4);
        float4 B2 = *(const float4*)(Bp + t * 16 + 8);
        float4 B3 = *(const float4*)(Bp + t * 16 + 12);
        float Bv[16] = {B0.x, B0.y, B0.z, B0.w, B1.x, B1.y, B1.z, B1.w,
                        B2.x, B2.y, B2.z, B2.w, B3.x, B3.y, B3.z, B3.w};
#pragma unroll
        for (int n = 0; n < 16; n++) {
            float dA = exp2f(dtv * a2[n]);
            h[n] = fmaf(dA, h[n], dx * Bv[n]);
        }
        sdt += dtv;
    }
    size_t cbase = ((size_t)((b * 2 + dh) * NCH + ck)) * 1024 + lane * 16;
#pragma unroll
    for (int j = 0; j < 4; j++) {
        *(float4*)(chH + cbase + j * 4) = make_float4(h[j * 4], h[j * 4 + 1], h[j * 4 + 2], h[j * 4 + 3]);
        *(float4*)(chP + cbase + j * 4) = make_float4(exp2f(a2[j * 4] * sdt), exp2f(a2[j * 4 + 1] * sdt),
                                                      exp2f(a2[j * 4 + 2] * sdt), exp2f(a2[j * 4 + 3] * sdt));
    }
}

// ---------------- Scan pass 2: 16384 independent scalar recurrences over 128 chunks ----------------
// thread -> (row = b*2+dh  [16], q = lane*16+n [1024]); consecutive threads = consecutive floats.
__global__ __launch_bounds__(64) void k_s2(float* __restrict__ chH,
                                           const float* __restrict__ chP) {
    int t = blockIdx.x * 64 + threadIdx.x;   // 0..16383
    int row = t >> 10;
    int q = t & 1023;
    size_t base = (size_t)row * NCH * 1024 + q;
    float H = 0.f;
#pragma unroll 8
    for (int ck = 0; ck < NCH; ck++) {
        size_t a = base + (size_t)ck * 1024;
        float h = chH[a];
        float p = chP[a];
        chH[a] = H;
        H = fmaf(p, H, h);
    }
}

// ---------------- Scan pass 3: re-scan from h_init, emit gated y (B,L,D) ----------------
__global__ __launch_bounds__(64) void k_s3(const float* __restrict__ xmg,
                                           const float* __restrict__ zg,
                                           const float* __restrict__ Bc2,
                                           const float* __restrict__ Cc2,
                                           const float* __restrict__ dtpI,
                                           const float* __restrict__ dtw,
                                           const float* __restrict__ dtb,
                                           const float* __restrict__ A_log,
                                           const float* __restrict__ Dpp,
                                           const float* __restrict__ hinit,
                                           float* __restrict__ Y) {
    int g = blockIdx.x;
    int ck = g & (NCH - 1);
    int dh = (g >> 7) & 1;
    int b = g >> 8;
    int lane = threadIdx.x;
    int d = dh * 64 + lane;
    float a2[16];
#pragma unroll
    for (int j = 0; j < 4; j++) {
        float4 v = *(const float4*)(A_log + d * 16 + j * 4);
        a2[j * 4 + 0] = -__expf(v.x) * 1.4426950408889634f;
        a2[j * 4 + 1] = -__expf(v.y) * 1.4426950408889634f;
        a2[j * 4 + 2] = -__expf(v.z) * 1.4426950408889634f;
        a2[j * 4 + 3] = -__expf(v.w) * 1.4426950408889634f;
    }
    float4 dw = *(const float4*)(dtw + d * 4);
    float dtbd = dtb[d];
    float Dpd = Dpp[d];
    size_t cbase = ((size_t)((b * 2 + dh) * NCH + ck)) * 1024 + lane * 16;
    float h[16];
#pragma unroll
    for (int j = 0; j < 4; j++) {
        float4 v = *(const float4*)(hinit + cbase + j * 4);
        h[j * 4 + 0] = v.x; h[j * 4 + 1] = v.y; h[j * 4 + 2] = v.z; h[j * 4 + 3] = v.w;
    }
    size_t bl0 = (size_t)b * LL + ck * CLEN;
    const float* xmp = xmg + bl0 * DD + d;
    const float* zp = zg + bl0 * DD + d;
    const float* Bp = Bc2 + bl0 * 16;
    const float* Cp = Cc2 + bl0 * 16;
    const float* dpp = dtpI + bl0 * 4;
    float* Yp = Y + bl0 * DD + d;
#pragma unroll 2
    for (int t = 0; t < CLEN; t++) {
        float xmv = xmp[(size_t)t * DD];
        float zv = zp[(size_t)t * DD];
        float4 q = *(const float4*)(dpp + t * 4);
        float tp = dtbd + q.x * dw.x + q.y * dw.y + q.z * dw.z + q.w * dw.w;
        float dtv = softplus_f(tp);
        float dx = dtv * xmv;
        float4 B0 = *(const float4*)(Bp + t * 16);
        float4 B1 = *(const float4*)(Bp + t * 16 + 4);
        float4 B2 = *(const float4*)(Bp + t * 16 + 8);
        float4 B3 = *(const float4*)(Bp + t * 16 + 12);
        float4 C0 = *(const float4*)(Cp + t * 16);
        float4 C1 = *(const float4*)(Cp + t * 16 + 4);
        float4 C2 = *(const float4*)(Cp + t * 16 + 8);
        float4 C3 = *(const float4*)(Cp + t * 16 + 12);
        float Bv[16] = {B0.x, B0.y, B0.z, B0.w, B1.x, B1.y, B1.z, B1.w,
                        B2.x, B2.y, B2.z, B2.w, B3.x, B3.y, B3.z, B3.w};
        float Cv[16] = {C0.x, C0.y, C0.z, C0.w, C1.x, C1.y, C1.z, C1.w,
                        C2.x, C2.y, C2.z, C2.w, C3.x, C3.y, C3.z, C3.w};
        float y0 = 0.f, y1 = 0.f, y2 = 0.f, y3 = 0.f;
#pragma unroll
        for (int n = 0; n < 16; n += 4) {
            float dA0 = exp2f(dtv * a2[n]);
            float dA1 = exp2f(dtv * a2[n + 1]);
            float dA2 = exp2f(dtv * a2[n + 2]);
            float dA3 = exp2f(dtv * a2[n + 3]);
            h[n] = fmaf(dA0, h[n], dx * Bv[n]);
            h[n + 1] = fmaf(dA1, h[n + 1], dx * Bv[n + 1]);
            h[n + 2] = fmaf(dA2, h[n + 2], dx * Bv[n + 2]);
            h[n + 3] = fmaf(dA3, h[n + 3], dx * Bv[n + 3]);
            y0 = fmaf(h[n], Cv[n], y0);
            y1 = fmaf(h[n + 1], Cv[n + 1], y1);
            y2 = fmaf(h[n + 2], Cv[n + 2], y2);
            y3 = fmaf(h[n + 3], Cv[n + 3], y3);
        }
        float yv = (y0 + y1) + (y2 + y3);
        yv = fmaf(xmv, Dpd, yv);
        Yp[(size_t)t * DD] = yv * silu_f(zv);
    }
}

// ---------------- K4: out_proj + PReLU -> out_tok (B,64,L) ----------------
__global__ __launch_bounds__(256) void k_outproj(const float* __restrict__ Y,
                                                 const float* __restrict__ wo,
                                                 const float* __restrict__ pre,
                                                 float* __restrict__ out_tok) {
    int blk = blockIdx.x;
    int half = blk & 1;
    int bl = (blk >> 1) * 256 + threadIdx.x;
    int oc0 = half * 32;
    const float* yr = Y + (size_t)bl * DD;
    float acc[32];
#pragma unroll
    for (int o = 0; o < 32; o++) acc[o] = 0.f;
    for (int c8 = 0; c8 < 8; c8++) {
        float4 v0 = *(const float4*)(yr + c8 * 16 + 0);
        float4 v1 = *(const float4*)(yr + c8 * 16 + 4);
        float4 v2 = *(const float4*)(yr + c8 * 16 + 8);
        float4 v3 = *(const float4*)(yr + c8 * 16 + 12);
        float xv[16] = {v0.x, v0.y, v0.z, v0.w, v1.x, v1.y, v1.z, v1.w,
                        v2.x, v2.y, v2.z, v2.w, v3.x, v3.y, v3.z, v3.w};
#pragma unroll
        for (int o = 0; o < 32; o++) {
            const float* wr = wo + (size_t)(oc0 + o) * DD + c8 * 16;
            float a = acc[o];
#pragma unroll
            for (int j = 0; j < 16; j++) a = fmaf(xv[j], wr[j], a);
            acc[o] = a;
        }
    }
    float pa = pre[0];
    int b = bl >> 12, l = bl & 4095;
    for (int o = 0; o < 32; o++) {
        float v = acc[o];
        v = v >= 0.f ? v : pa * v;
        out_tok[((size_t)b * 64 + oc0 + o) * LL + l] = v;
    }
}

// ---------------- K5/K6: 3x3 conv + BN + PReLU (+residual add) ----------------
template <bool TR, bool ADD>
__global__ __launch_bounds__(256) void k_conv3(const float* __restrict__ inp,
                                               const float* __restrict__ w,
                                               const float* __restrict__ bnp,
                                               const float* __restrict__ pre,
                                               const float* __restrict__ addp,
                                               float* __restrict__ outp) {
    int bid = blockIdx.x;
    int b = bid >> 6;
    int tile = bid & 63;
    int i0 = (tile >> 3) * 8;
    int j0 = (tile & 7) * 8;
    int pos = threadIdx.x & 63;
    int ocg = threadIdx.x >> 6;
    int ti = pos >> 3, tj = pos & 7;
    __shared__ float in_t[64][10][10];
    const float* ib = inp + (size_t)b * 64 * LL;
    for (int idx = threadIdx.x; idx < 6400; idx += 256) {
        int ic, pp, qq;
        if (TR) {
            pp = idx % 10;
            int rem = idx / 10;
            qq = rem % 10;
            ic = rem / 10;
        } else {
            qq = idx % 10;
            int rem = idx / 10;
            pp = rem % 10;
            ic = rem / 10;
        }
        int p = i0 - 1 + pp, qv = j0 - 1 + qq;
        float v = 0.f;
        if (p >= 0 && p < 64 && qv >= 0 && qv < 64)
            v = TR ? ib[ic * LL + qv * 64 + p] : ib[ic * LL + p * 64 + qv];
        in_t[ic][pp][qq] = v;
    }
    __syncthreads();
    float acc[16];
#pragma unroll
    for (int o = 0; o < 16; o++) acc[o] = 0.f;
    int oc0 = __builtin_amdgcn_readfirstlane(ocg) * 16;
    for (int ic = 0; ic < 64; ic++) {
        float iv[3][3];
#pragma unroll
        for (int di = 0; di < 3; di++)
#pragma unroll
            for (int dj = 0; dj < 3; dj++) iv[di][dj] = in_t[ic][ti + di][tj + dj];
#pragma unroll
        for (int o = 0; o < 16; o++) {
            const float* wr = w + ((size_t)(oc0 + o) * 64 + ic) * 9;
            float a = acc[o];
            a = fmaf(iv[0][0], wr[0], a);
            a = fmaf(iv[0][1], wr[1], a);
            a = fmaf(iv[0][2], wr[2], a);
            a = fmaf(iv[1][0], wr[3], a);
            a = fmaf(iv[1][1], wr[4], a);
            a = fmaf(iv[1][2], wr[5], a);
            a = fmaf(iv[2][0], wr[6], a);
            a = fmaf(iv[2][1], wr[7], a);
            a = fmaf(iv[2][2], wr[8], a);
            acc[o] = a;
        }
    }
    float pa = pre[0];
#pragma unroll
    for (int o = 0; o < 16; o++) {
        int oc = oc0 + o;
        float g = bnp[oc], be = bnp[64 + oc], m = bnp[128 + oc], vv = bnp[192 + oc];
        float sc = g * rsqrtf(vv + EPS);
        float sh = be - m * sc;
        float v = fmaf(acc[o], sc, sh);
        v = v >= 0.f ? v : pa * v;
        size_t addr = ((size_t)b * 64 + oc) * LL + (i0 + ti) * 64 + (j0 + tj);
        if (ADD) v += addp[addr];
        outp[addr] = v;
    }
}

extern "C" void kernel_launch(void* const* d_in, const int* in_sizes, int n_in,
                              void* d_out, int out_size, void* d_ws, size_t ws_size,
                              hipStream_t stream) {
    const float* x = (const float*)d_in[0];
    const float* in_proj_w = (const float*)d_in[1];
    const float* conv1d_w = (const float*)d_in[2];
    const float* conv1d_b = (const float*)d_in[3];
    const float* x_proj_w = (const float*)d_in[4];
    const float* dt_proj_w = (const float*)d_in[5];
    const float* dt_proj_b = (const float*)d_in[6];
    const float* A_log = (const float*)d_in[7];
    const float* Dp = (const float*)d_in[8];
    const float* out_proj_w = (const float*)d_in[9];
    const float* prelu_ssm = (const float*)d_in[10];
    const float* res_w = (const float*)d_in[11];
    const float* res_bn = (const float*)d_in[12];
    const float* conv1_w = (const float*)d_in[13];
    const float* bn1 = (const float*)d_in[14];
    const float* prelu1 = (const float*)d_in[15];
    const float* conv2_w = (const float*)d_in[16];
    const float* bn2 = (const float*)d_in[17];
    const float* prelu2 = (const float*)d_in[18];
    float* out = (float*)d_out;
    float* ws = (float*)d_ws;

    const size_t S = (size_t)BB * LL * DD;        // 4,194,304
    const size_t HALF = S / 2;                    // 2,097,152
    float* xm_raw = ws;                           // [0,S) dead after conv1d
    float* chH = ws;                              // reuse  [0,HALF)
    float* chP = ws + HALF;                       //        [HALF,S)
    float* xmg = ws + S;                          // (B,L,D); reused as out_tok after s3
    float* zg = ws + 2 * S;                       // (B,L,D); reused as img2 after s3
    float* Yb = ws + 3 * S;                       // (B,L,D)
    float* Bc2 = ws + 4 * S;                      // B*L*16
    float* Cc2 = Bc2 + (size_t)BB * LL * 16;
    float* dtp = Cc2 + (size_t)BB * LL * 16;      // B*L*4
    float* out_tok = xmg;
    float* img2 = zg;

    k_res<<<dim3(128), dim3(256), 0, stream>>>(x, res_w, res_bn, out);
    k_inproj<<<dim3(512), dim3(256), 0, stream>>>(x, in_proj_w, xm_raw, zg);
    k_conv1d<<<dim3(512), dim3(256), 0, stream>>>(xm_raw, conv1d_w, conv1d_b, xmg);
    k_xproj_bc<<<dim3(128), dim3(256), 0, stream>>>(xmg, x_proj_w, Bc2, Cc2, dtp);
    k_s1<<<dim3(BB * 2 * NCH), dim3(64), 0, stream>>>(xmg, Bc2, dtp, dt_proj_w, dt_proj_b, A_log, chH, chP);
    k_s2<<<dim3(256), dim3(64), 0, stream>>>(chH, chP);
    k_s3<<<dim3(BB * 2 * NCH), dim3(64), 0, stream>>>(xmg, zg, Bc2, Cc2, dtp, dt_proj_w, dt_proj_b,
                                                      A_log, Dp, chH, Yb);
    k_outproj<<<dim3(256), dim3(256), 0, stream>>>(Yb, out_proj_w, prelu_ssm, out_tok);
    k_conv3<true, false><<<dim3(512), dim3(256), 0, stream>>>(out_tok, conv1_w, bn1, prelu1, nullptr, img2);
    k_conv3<false, true><<<dim3(512), dim3(256), 0, stream>>>(img2, conv2_w, bn2, prelu2, out, out);
}

// Round 4
// 361.063 us; speedup vs baseline: 1.8459x; 1.4582x over previous
//
#include <hip/hip_runtime.h>
#include <hip/hip_bf16.h>

#define BB 8
#define CC 64
#define LL 4096
#define DD 128
#define NN 16
#define EPS 1e-5f
#define NCH 128
#define CLEN 32

typedef short short8 __attribute__((ext_vector_type(8)));
typedef unsigned short ushort8v __attribute__((ext_vector_type(8)));
typedef float f32x4 __attribute__((ext_vector_type(4)));

__device__ __forceinline__ float silu_f(float v) {
    return v / (1.f + __expf(-v));
}
__device__ __forceinline__ float softplus_f(float t) {
    return fmaxf(t, 0.f) + __logf(1.f + __expf(-fabsf(t)));
}
__device__ __forceinline__ unsigned short f2bf(float f) {
    unsigned int u = __float_as_uint(f);
    u += 0x7fff + ((u >> 16) & 1);
    return (unsigned short)(u >> 16);
}

// ---------------- K0: residual 1x1 conv + BN -> d_out ----------------
__global__ __launch_bounds__(256) void k_res(const float* __restrict__ x,
                                             const float* __restrict__ rw,
                                             const float* __restrict__ rbn,
                                             float* __restrict__ out) {
    int b = blockIdx.x >> 4;
    int s = ((blockIdx.x & 15) << 8) + threadIdx.x;
    const float* xb = x + (size_t)b * CC * LL;
    float xv[64];
#pragma unroll
    for (int ic = 0; ic < 64; ic++) xv[ic] = xb[ic * LL + s];
    for (int oc = 0; oc < 64; oc++) {
        float acc = 0.f;
#pragma unroll
        for (int ic = 0; ic < 64; ic++) acc = fmaf(xv[ic], rw[oc * 64 + ic], acc);
        float g = rbn[oc], be = rbn[64 + oc], m = rbn[128 + oc], v = rbn[192 + oc];
        float sc = g * rsqrtf(v + EPS);
        float sh = be - m * sc;
        out[((size_t)b * 64 + oc) * LL + s] = fmaf(acc, sc, sh);
    }
}

// ---------------- K1: in_proj GEMM -> xm_raw (B,D,L), zg (B,L,D) ----------------
__global__ __launch_bounds__(256) void k_inproj(const float* __restrict__ x,
                                                const float* __restrict__ w,
                                                float* __restrict__ xm_raw,
                                                float* __restrict__ zg) {
    int b = blockIdx.x >> 6;
    int l0 = (blockIdx.x & 63) << 6;
    int lane = threadIdx.x & 63;
    int jg = threadIdx.x >> 6;
    int jb = __builtin_amdgcn_readfirstlane(jg);
    int l = l0 + lane;
    __shared__ float z_t[128][65];
    const float* xb = x + (size_t)b * CC * LL;
    float xv[64];
#pragma unroll
    for (int c = 0; c < 64; c++) xv[c] = xb[c * LL + l];
    const float* wrow = w + jb * 64 * 64;
    if (jb < 2) {
        float* ob = xm_raw + ((size_t)b * DD + jb * 64) * LL + l0;
        for (int jj = 0; jj < 64; jj++) {
            float acc = 0.f;
#pragma unroll
            for (int c = 0; c < 64; c++) acc = fmaf(xv[c], wrow[jj * 64 + c], acc);
            ob[(size_t)jj * LL + lane] = acc;
        }
    } else {
        int zd0 = (jb - 2) * 64;
        for (int jj = 0; jj < 64; jj++) {
            float acc = 0.f;
#pragma unroll
            for (int c = 0; c < 64; c++) acc = fmaf(xv[c], wrow[jj * 64 + c], acc);
            z_t[zd0 + jj][lane] = acc;
        }
    }
    __syncthreads();
    int d = threadIdx.x & 127, lsub = threadIdx.x >> 7;
    float* zb = zg + ((size_t)b * LL + l0) * DD;
    for (int p = 0; p < 32; p++) {
        int ll = p * 2 + lsub;
        zb[(size_t)ll * DD + d] = z_t[d][ll];
    }
}

// ---------------- K1b: causal depthwise conv1d (k=4) + SiLU -> xmg (B,L,D) ----------------
__global__ __launch_bounds__(256) void k_conv1d(const float* __restrict__ xm_raw,
                                                const float* __restrict__ cw,
                                                const float* __restrict__ cb,
                                                float* __restrict__ xmg) {
    int b = blockIdx.x >> 6;
    int l0 = (blockIdx.x & 63) << 6;
    __shared__ float s[128][69];
    for (int idx = threadIdx.x; idx < 128 * 67; idx += 256) {
        int row = idx / 67, col = idx % 67;
        int l = l0 - 3 + col;
        s[row][col] = (l >= 0) ? xm_raw[((size_t)b * DD + row) * LL + l] : 0.f;
    }
    __syncthreads();
    int d = threadIdx.x & 127, lsub = threadIdx.x >> 7;
    float w0 = cw[d * 4], w1 = cw[d * 4 + 1], w2 = cw[d * 4 + 2], w3 = cw[d * 4 + 3];
    float bb = cb[d];
    float* ob = xmg + ((size_t)b * LL + l0) * DD;
#pragma unroll 4
    for (int i = 0; i < 32; i++) {
        int ll = i * 2 + lsub;
        float v = bb + w0 * s[d][ll] + w1 * s[d][ll + 1] + w2 * s[d][ll + 2] + w3 * s[d][ll + 3];
        ob[(size_t)ll * DD + d] = silu_f(v);
    }
}

// ---------------- K2: x_proj -> Bc2 (B,L,16), Cc2 (B,L,16), dtp (B,L,4) ----------------
__global__ __launch_bounds__(256) void k_xproj_bc(const float* __restrict__ xmg,
                                                  const float* __restrict__ xw,
                                                  float* __restrict__ Bc2,
                                                  float* __restrict__ Cc2,
                                                  float* __restrict__ dtpO) {
    int bl = blockIdx.x * 256 + threadIdx.x;
    const float* xr = xmg + (size_t)bl * DD;
    float acc[36];
#pragma unroll
    for (int j = 0; j < 36; j++) acc[j] = 0.f;
    for (int c8 = 0; c8 < 8; c8++) {
        float4 v0 = *(const float4*)(xr + c8 * 16 + 0);
        float4 v1 = *(const float4*)(xr + c8 * 16 + 4);
        float4 v2 = *(const float4*)(xr + c8 * 16 + 8);
        float4 v3 = *(const float4*)(xr + c8 * 16 + 12);
        float xv[16] = {v0.x, v0.y, v0.z, v0.w, v1.x, v1.y, v1.z, v1.w,
                        v2.x, v2.y, v2.z, v2.w, v3.x, v3.y, v3.z, v3.w};
#pragma unroll
        for (int jj = 0; jj < 36; jj++) {
            const float* wr = xw + jj * DD + c8 * 16;
            float a = acc[jj];
#pragma unroll
            for (int j = 0; j < 16; j++) a = fmaf(xv[j], wr[j], a);
            acc[jj] = a;
        }
    }
    *(float4*)(dtpO + (size_t)bl * 4) = make_float4(acc[0], acc[1], acc[2], acc[3]);
    float* Bp = Bc2 + (size_t)bl * 16;
    float* Cp = Cc2 + (size_t)bl * 16;
#pragma unroll
    for (int q = 0; q < 4; q++) {
        *(float4*)(Bp + q * 4) = make_float4(acc[4 + q * 4], acc[5 + q * 4], acc[6 + q * 4], acc[7 + q * 4]);
        *(float4*)(Cp + q * 4) = make_float4(acc[20 + q * 4], acc[21 + q * 4], acc[22 + q * 4], acc[23 + q * 4]);
    }
}

// ---------------- Scan pass 1 ----------------
__global__ __launch_bounds__(64) void k_s1(const float* __restrict__ xmg,
                                           const float* __restrict__ Bc2,
                                           const float* __restrict__ dtpI,
                                           const float* __restrict__ dtw,
                                           const float* __restrict__ dtb,
                                           const float* __restrict__ A_log,
                                           float* __restrict__ chH,
                                           float* __restrict__ chP) {
    int g = blockIdx.x;
    int ck = g & (NCH - 1);
    int dh = (g >> 7) & 1;
    int b = g >> 8;
    int lane = threadIdx.x;
    int d = dh * 64 + lane;
    float a2[16];
#pragma unroll
    for (int j = 0; j < 4; j++) {
        float4 v = *(const float4*)(A_log + d * 16 + j * 4);
        a2[j * 4 + 0] = -__expf(v.x) * 1.4426950408889634f;
        a2[j * 4 + 1] = -__expf(v.y) * 1.4426950408889634f;
        a2[j * 4 + 2] = -__expf(v.z) * 1.4426950408889634f;
        a2[j * 4 + 3] = -__expf(v.w) * 1.4426950408889634f;
    }
    float4 dw = *(const float4*)(dtw + d * 4);
    float dtbd = dtb[d];
    float h[16];
#pragma unroll
    for (int n = 0; n < 16; n++) h[n] = 0.f;
    float sdt = 0.f;
    size_t bl0 = (size_t)b * LL + ck * CLEN;
    const float* xmp = xmg + bl0 * DD + d;
    const float* Bp = Bc2 + bl0 * 16;
    const float* dpp = dtpI + bl0 * 4;
#pragma unroll 2
    for (int t = 0; t < CLEN; t++) {
        float xmv = xmp[(size_t)t * DD];
        float4 q = *(const float4*)(dpp + t * 4);
        float tp = dtbd + q.x * dw.x + q.y * dw.y + q.z * dw.z + q.w * dw.w;
        float dtv = softplus_f(tp);
        float dx = dtv * xmv;
        float4 B0 = *(const float4*)(Bp + t * 16);
        float4 B1 = *(const float4*)(Bp + t * 16 + 4);
        float4 B2 = *(const float4*)(Bp + t * 16 + 8);
        float4 B3 = *(const float4*)(Bp + t * 16 + 12);
        float Bv[16] = {B0.x, B0.y, B0.z, B0.w, B1.x, B1.y, B1.z, B1.w,
                        B2.x, B2.y, B2.z, B2.w, B3.x, B3.y, B3.z, B3.w};
#pragma unroll
        for (int n = 0; n < 16; n++) {
            float dA = exp2f(dtv * a2[n]);
            h[n] = fmaf(dA, h[n], dx * Bv[n]);
        }
        sdt += dtv;
    }
    size_t cbase = ((size_t)((b * 2 + dh) * NCH + ck)) * 1024 + lane * 16;
#pragma unroll
    for (int j = 0; j < 4; j++) {
        *(float4*)(chH + cbase + j * 4) = make_float4(h[j * 4], h[j * 4 + 1], h[j * 4 + 2], h[j * 4 + 3]);
        *(float4*)(chP + cbase + j * 4) = make_float4(exp2f(a2[j * 4] * sdt), exp2f(a2[j * 4 + 1] * sdt),
                                                      exp2f(a2[j * 4 + 2] * sdt), exp2f(a2[j * 4 + 3] * sdt));
    }
}

// ---------------- Scan pass 2 ----------------
__global__ __launch_bounds__(64) void k_s2(float* __restrict__ chH,
                                           const float* __restrict__ chP) {
    int t = blockIdx.x * 64 + threadIdx.x;   // 0..16383
    int row = t >> 10;
    int q = t & 1023;
    size_t base = (size_t)row * NCH * 1024 + q;
    float H = 0.f;
#pragma unroll 8
    for (int ck = 0; ck < NCH; ck++) {
        size_t a = base + (size_t)ck * 1024;
        float h = chH[a];
        float p = chP[a];
        chH[a] = H;
        H = fmaf(p, H, h);
    }
}

// ---------------- Scan pass 3 ----------------
__global__ __launch_bounds__(64) void k_s3(const float* __restrict__ xmg,
                                           const float* __restrict__ zg,
                                           const float* __restrict__ Bc2,
                                           const float* __restrict__ Cc2,
                                           const float* __restrict__ dtpI,
                                           const float* __restrict__ dtw,
                                           const float* __restrict__ dtb,
                                           const float* __restrict__ A_log,
                                           const float* __restrict__ Dpp,
                                           const float* __restrict__ hinit,
                                           float* __restrict__ Y) {
    int g = blockIdx.x;
    int ck = g & (NCH - 1);
    int dh = (g >> 7) & 1;
    int b = g >> 8;
    int lane = threadIdx.x;
    int d = dh * 64 + lane;
    float a2[16];
#pragma unroll
    for (int j = 0; j < 4; j++) {
        float4 v = *(const float4*)(A_log + d * 16 + j * 4);
        a2[j * 4 + 0] = -__expf(v.x) * 1.4426950408889634f;
        a2[j * 4 + 1] = -__expf(v.y) * 1.4426950408889634f;
        a2[j * 4 + 2] = -__expf(v.z) * 1.4426950408889634f;
        a2[j * 4 + 3] = -__expf(v.w) * 1.4426950408889634f;
    }
    float4 dw = *(const float4*)(dtw + d * 4);
    float dtbd = dtb[d];
    float Dpd = Dpp[d];
    size_t cbase = ((size_t)((b * 2 + dh) * NCH + ck)) * 1024 + lane * 16;
    float h[16];
#pragma unroll
    for (int j = 0; j < 4; j++) {
        float4 v = *(const float4*)(hinit + cbase + j * 4);
        h[j * 4 + 0] = v.x; h[j * 4 + 1] = v.y; h[j * 4 + 2] = v.z; h[j * 4 + 3] = v.w;
    }
    size_t bl0 = (size_t)b * LL + ck * CLEN;
    const float* xmp = xmg + bl0 * DD + d;
    const float* zp = zg + bl0 * DD + d;
    const float* Bp = Bc2 + bl0 * 16;
    const float* Cp = Cc2 + bl0 * 16;
    const float* dpp = dtpI + bl0 * 4;
    float* Yp = Y + bl0 * DD + d;
#pragma unroll 2
    for (int t = 0; t < CLEN; t++) {
        float xmv = xmp[(size_t)t * DD];
        float zv = zp[(size_t)t * DD];
        float4 q = *(const float4*)(dpp + t * 4);
        float tp = dtbd + q.x * dw.x + q.y * dw.y + q.z * dw.z + q.w * dw.w;
        float dtv = softplus_f(tp);
        float dx = dtv * xmv;
        float4 B0 = *(const float4*)(Bp + t * 16);
        float4 B1 = *(const float4*)(Bp + t * 16 + 4);
        float4 B2 = *(const float4*)(Bp + t * 16 + 8);
        float4 B3 = *(const float4*)(Bp + t * 16 + 12);
        float4 C0 = *(const float4*)(Cp + t * 16);
        float4 C1 = *(const float4*)(Cp + t * 16 + 4);
        float4 C2 = *(const float4*)(Cp + t * 16 + 8);
        float4 C3 = *(const float4*)(Cp + t * 16 + 12);
        float Bv[16] = {B0.x, B0.y, B0.z, B0.w, B1.x, B1.y, B1.z, B1.w,
                        B2.x, B2.y, B2.z, B2.w, B3.x, B3.y, B3.z, B3.w};
        float Cv[16] = {C0.x, C0.y, C0.z, C0.w, C1.x, C1.y, C1.z, C1.w,
                        C2.x, C2.y, C2.z, C2.w, C3.x, C3.y, C3.z, C3.w};
        float y0 = 0.f, y1 = 0.f, y2 = 0.f, y3 = 0.f;
#pragma unroll
        for (int n = 0; n < 16; n += 4) {
            float dA0 = exp2f(dtv * a2[n]);
            float dA1 = exp2f(dtv * a2[n + 1]);
            float dA2 = exp2f(dtv * a2[n + 2]);
            float dA3 = exp2f(dtv * a2[n + 3]);
            h[n] = fmaf(dA0, h[n], dx * Bv[n]);
            h[n + 1] = fmaf(dA1, h[n + 1], dx * Bv[n + 1]);
            h[n + 2] = fmaf(dA2, h[n + 2], dx * Bv[n + 2]);
            h[n + 3] = fmaf(dA3, h[n + 3], dx * Bv[n + 3]);
            y0 = fmaf(h[n], Cv[n], y0);
            y1 = fmaf(h[n + 1], Cv[n + 1], y1);
            y2 = fmaf(h[n + 2], Cv[n + 2], y2);
            y3 = fmaf(h[n + 3], Cv[n + 3], y3);
        }
        float yv = (y0 + y1) + (y2 + y3);
        yv = fmaf(xmv, Dpd, yv);
        Yp[(size_t)t * DD] = yv * silu_f(zv);
    }
}

// ---------------- K4: out_proj + PReLU -> img1t bf16 [b][p*64+q][64], px(p,q): l = q*64+p ----------------
__global__ __launch_bounds__(256) void k_outproj(const float* __restrict__ Y,
                                                 const float* __restrict__ wo,
                                                 const float* __restrict__ pre,
                                                 unsigned short* __restrict__ img1t) {
    int blk = blockIdx.x;
    int half = blk & 1;
    int bl = (blk >> 1) * 256 + threadIdx.x;
    int oc0 = half * 32;
    const float* yr = Y + (size_t)bl * DD;
    float acc[32];
#pragma unroll
    for (int o = 0; o < 32; o++) acc[o] = 0.f;
    for (int c8 = 0; c8 < 8; c8++) {
        float4 v0 = *(const float4*)(yr + c8 * 16 + 0);
        float4 v1 = *(const float4*)(yr + c8 * 16 + 4);
        float4 v2 = *(const float4*)(yr + c8 * 16 + 8);
        float4 v3 = *(const float4*)(yr + c8 * 16 + 12);
        float xv[16] = {v0.x, v0.y, v0.z, v0.w, v1.x, v1.y, v1.z, v1.w,
                        v2.x, v2.y, v2.z, v2.w, v3.x, v3.y, v3.z, v3.w};
#pragma unroll
        for (int o = 0; o < 32; o++) {
            const float* wr = wo + (size_t)(oc0 + o) * DD + c8 * 16;
            float a = acc[o];
#pragma unroll
            for (int j = 0; j < 16; j++) a = fmaf(xv[j], wr[j], a);
            acc[o] = a;
        }
    }
    float pa = pre[0];
    int b = bl >> 12, l = bl & 4095;
    int px = (l & 63) * 64 + (l >> 6);           // (p = l%64, q = l/64)
    unsigned short* dst = img1t + ((size_t)b * 4096 + px) * 64 + oc0;
#pragma unroll
    for (int g8 = 0; g8 < 4; g8++) {
        ushort8v w;
#pragma unroll
        for (int j = 0; j < 8; j++) {
            float v = acc[g8 * 8 + j];
            v = v >= 0.f ? v : pa * v;
            w[j] = f2bf(v);
        }
        *(ushort8v*)(dst + g8 * 8) = w;
    }
}

// ---------------- weight prep: Wk[oc][shift*64+ic] bf16 for both 3x3 convs ----------------
__global__ __launch_bounds__(256) void k_wprep(const float* __restrict__ w1,
                                               const float* __restrict__ w2,
                                               unsigned short* __restrict__ Wk1,
                                               unsigned short* __restrict__ Wk2) {
    int idx = blockIdx.x * 256 + threadIdx.x;
    if (idx >= 2 * 36864) return;
    const float* w = (idx < 36864) ? w1 : w2;
    unsigned short* dst = (idx < 36864) ? Wk1 : Wk2;
    int r = (idx < 36864) ? idx : idx - 36864;
    int oc = r / 576, k = r % 576;
    int shift = k >> 6, ic = k & 63;
    dst[oc * 576 + k] = f2bf(w[(oc * 64 + ic) * 9 + shift]);
}

// ---------------- K5/K6: 3x3 conv via MFMA bf16 + BN + PReLU (+residual) ----------------
// in_t: bf16 [b][p*64+q][64ic]. FINAL=false: out bf16 same layout. FINAL=true: f32 CHW += residual.
template <bool FINAL>
__global__ __launch_bounds__(256) void k_conv3m(const unsigned short* __restrict__ in_t,
                                                const unsigned short* __restrict__ Wk,
                                                const float* __restrict__ bnp,
                                                const float* __restrict__ pre,
                                                unsigned short* __restrict__ out_t,
                                                float* __restrict__ outf) {
    int bid = blockIdx.x;
    int b = bid >> 6;
    int p = bid & 63;
    int tid = threadIdx.x;
    int lane = tid & 63;
    int wv = tid >> 6;
    int oc0 = __builtin_amdgcn_readfirstlane(wv * 16);
    __shared__ unsigned short lds[3 * 66 * 64];

    // A fragments: weights for this wave's 16 oc, all 18 k-steps (held in VGPRs)
    short8 afrag[18];
    const unsigned short* wrow = Wk + (size_t)(oc0 + (lane & 15)) * 576 + ((lane >> 4) * 8);
#pragma unroll
    for (int s = 0; s < 18; s++) afrag[s] = *(const short8*)(wrow + s * 32);

    // stage rows p-1..p+1, cols -1..64, 64ic bf16, 16B chunks XOR-swizzled by (col&7)
    const unsigned short* ib = in_t + (size_t)b * 4096 * 64;
    for (int idx = tid; idx < 1584; idx += 256) {
        int pair = idx >> 3, c = idx & 7;
        int di = pair / 66, col = pair % 66;
        int r = p - 1 + di, q = col - 1;
        ushort8v v = {0, 0, 0, 0, 0, 0, 0, 0};
        if (r >= 0 && r < 64 && q >= 0 && q < 64)
            v = *(const ushort8v*)(ib + ((size_t)(r * 64 + q)) * 64 + c * 8);
        *(ushort8v*)(lds + pair * 64 + ((c ^ (col & 7)) * 8)) = v;
    }
    __syncthreads();

    f32x4 acc[4];
#pragma unroll
    for (int n0 = 0; n0 < 4; n0++) acc[n0] = (f32x4){0.f, 0.f, 0.f, 0.f};
#pragma unroll
    for (int s = 0; s < 18; s++) {
        const int shift = s >> 1, h = s & 1;
        const int di = shift / 3, dj = shift % 3;
#pragma unroll
        for (int n0 = 0; n0 < 4; n0++) {
            int col = n0 * 16 + (lane & 15) + dj;
            int off = (di * 66 + col) * 64 + (((h * 4 + (lane >> 4)) ^ (col & 7)) * 8);
            short8 bfrag = *(const short8*)(lds + off);
            acc[n0] = __builtin_amdgcn_mfma_f32_16x16x32_bf16(afrag[s], bfrag, acc[n0], 0, 0, 0);
        }
    }

    // epilogue: lane holds oc = ocb..ocb+3 (reg), px col q = n0*16 + (lane&15)
    int ocb = oc0 + ((lane >> 4) << 2);
    float4 g4 = *(const float4*)(bnp + ocb);
    float4 be4 = *(const float4*)(bnp + 64 + ocb);
    float4 m4 = *(const float4*)(bnp + 128 + ocb);
    float4 v4 = *(const float4*)(bnp + 192 + ocb);
    float sc[4], sh[4];
    sc[0] = g4.x * rsqrtf(v4.x + EPS); sh[0] = be4.x - m4.x * sc[0];
    sc[1] = g4.y * rsqrtf(v4.y + EPS); sh[1] = be4.y - m4.y * sc[1];
    sc[2] = g4.z * rsqrtf(v4.z + EPS); sh[2] = be4.z - m4.z * sc[2];
    sc[3] = g4.w * rsqrtf(v4.w + EPS); sh[3] = be4.w - m4.w * sc[3];
    float pa = pre[0];
#pragma unroll
    for (int n0 = 0; n0 < 4; n0++) {
        int q = n0 * 16 + (lane & 15);
        float vals[4];
#pragma unroll
        for (int r = 0; r < 4; r++) {
            float v = fmaf(acc[n0][r], sc[r], sh[r]);
            vals[r] = v >= 0.f ? v : pa * v;
        }
        if (FINAL) {
#pragma unroll
            for (int r = 0; r < 4; r++) {
                size_t addr = ((size_t)b * 64 + ocb + r) * 4096 + p * 64 + q;
                outf[addr] = vals[r] + outf[addr];
            }
        } else {
            ushort4 u = make_ushort4(f2bf(vals[0]), f2bf(vals[1]), f2bf(vals[2]), f2bf(vals[3]));
            *(ushort4*)(out_t + ((size_t)b * 4096 + p * 64 + q) * 64 + ocb) = u;
        }
    }
}

extern "C" void kernel_launch(void* const* d_in, const int* in_sizes, int n_in,
                              void* d_out, int out_size, void* d_ws, size_t ws_size,
                              hipStream_t stream) {
    const float* x = (const float*)d_in[0];
    const float* in_proj_w = (const float*)d_in[1];
    const float* conv1d_w = (const float*)d_in[2];
    const float* conv1d_b = (const float*)d_in[3];
    const float* x_proj_w = (const float*)d_in[4];
    const float* dt_proj_w = (const float*)d_in[5];
    const float* dt_proj_b = (const float*)d_in[6];
    const float* A_log = (const float*)d_in[7];
    const float* Dp = (const float*)d_in[8];
    const float* out_proj_w = (const float*)d_in[9];
    const float* prelu_ssm = (const float*)d_in[10];
    const float* res_w = (const float*)d_in[11];
    const float* res_bn = (const float*)d_in[12];
    const float* conv1_w = (const float*)d_in[13];
    const float* bn1 = (const float*)d_in[14];
    const float* prelu1 = (const float*)d_in[15];
    const float* conv2_w = (const float*)d_in[16];
    const float* bn2 = (const float*)d_in[17];
    const float* prelu2 = (const float*)d_in[18];
    float* out = (float*)d_out;
    float* ws = (float*)d_ws;

    const size_t S = (size_t)BB * LL * DD;        // 4,194,304
    const size_t HALF = S / 2;                    // 2,097,152
    float* xm_raw = ws;                           // [0,S) dead after conv1d
    float* chH = ws;                              // [0,HALF) live s1..s3
    float* chP = ws + HALF;                       // [HALF,S) live s1..s2
    float* xmg = ws + S;
    float* zg = ws + 2 * S;
    float* Yb = ws + 3 * S;
    float* Bc2 = ws + 4 * S;                      // B*L*16; dead after s3 -> reused for Wk
    float* Cc2 = Bc2 + (size_t)BB * LL * 16;
    float* dtp = Cc2 + (size_t)BB * LL * 16;      // B*L*4
    unsigned short* img1t = (unsigned short*)ws;              // [0, 1M floats) after s3
    unsigned short* img2t = (unsigned short*)(ws + HALF);     // [HALF, HALF+1M floats)
    unsigned short* Wk1 = (unsigned short*)Bc2;               // 36864 bf16
    unsigned short* Wk2 = Wk1 + 36864;

    k_res<<<dim3(128), dim3(256), 0, stream>>>(x, res_w, res_bn, out);
    k_inproj<<<dim3(512), dim3(256), 0, stream>>>(x, in_proj_w, xm_raw, zg);
    k_conv1d<<<dim3(512), dim3(256), 0, stream>>>(xm_raw, conv1d_w, conv1d_b, xmg);
    k_xproj_bc<<<dim3(128), dim3(256), 0, stream>>>(xmg, x_proj_w, Bc2, Cc2, dtp);
    k_s1<<<dim3(BB * 2 * NCH), dim3(64), 0, stream>>>(xmg, Bc2, dtp, dt_proj_w, dt_proj_b, A_log, chH, chP);
    k_s2<<<dim3(256), dim3(64), 0, stream>>>(chH, chP);
    k_s3<<<dim3(BB * 2 * NCH), dim3(64), 0, stream>>>(xmg, zg, Bc2, Cc2, dtp, dt_proj_w, dt_proj_b,
                                                      A_log, Dp, chH, Yb);
    k_outproj<<<dim3(256), dim3(256), 0, stream>>>(Yb, out_proj_w, prelu_ssm, img1t);
    k_wprep<<<dim3(288), dim3(256), 0, stream>>>(conv1_w, conv2_w, Wk1, Wk2);
    k_conv3m<false><<<dim3(512), dim3(256), 0, stream>>>(img1t, Wk1, bn1, prelu1, img2t, nullptr);
    k_conv3m<true><<<dim3(512), dim3(256), 0, stream>>>(img2t, Wk2, bn2, prelu2, nullptr, out);
}

// Round 5
// 242.949 us; speedup vs baseline: 2.7433x; 1.4862x over previous
//
#include <hip/hip_runtime.h>
#include <hip/hip_bf16.h>

#define BB 8
#define CC 64
#define LL 4096
#define DD 128
#define NN 16
#define EPS 1e-5f
#define NCH 128
#define CLEN 32

typedef short short8 __attribute__((ext_vector_type(8)));
typedef unsigned short ushort8v __attribute__((ext_vector_type(8)));
typedef float f32x4 __attribute__((ext_vector_type(4)));

__device__ __forceinline__ float silu_f(float v) {
    return v / (1.f + __expf(-v));
}
__device__ __forceinline__ float softplus_f(float t) {
    return fmaxf(t, 0.f) + __logf(1.f + __expf(-fabsf(t)));
}
__device__ __forceinline__ unsigned short f2bf(float f) {
    unsigned int u = __float_as_uint(f);
    u += 0x7fff + ((u >> 16) & 1);
    return (unsigned short)(u >> 16);
}

// ---------------- K0: residual 1x1 conv + BN -> d_out  (4 oc-groups/wave) ----------------
__global__ __launch_bounds__(256) void k_res(const float* __restrict__ x,
                                             const float* __restrict__ rw,
                                             const float* __restrict__ rbn,
                                             float* __restrict__ out) {
    int blk = blockIdx.x;                       // 512
    int b = blk >> 6;
    int s = ((blk & 63) << 6) + (threadIdx.x & 63);
    int oc0 = __builtin_amdgcn_readfirstlane(threadIdx.x >> 6) * 16;
    const float* xb = x + (size_t)b * CC * LL;
    float xv[64];
#pragma unroll
    for (int ic = 0; ic < 64; ic++) xv[ic] = xb[ic * LL + s];
#pragma unroll
    for (int o = 0; o < 16; o++) {
        int oc = oc0 + o;
        const float* wr = rw + oc * 64;
        float acc = 0.f;
#pragma unroll
        for (int ic = 0; ic < 64; ic++) acc = fmaf(xv[ic], wr[ic], acc);
        float g = rbn[oc], be = rbn[64 + oc], m = rbn[128 + oc], v = rbn[192 + oc];
        float sc = g * rsqrtf(v + EPS);
        float sh = be - m * sc;
        out[((size_t)b * 64 + oc) * LL + s] = fmaf(acc, sc, sh);
    }
}

// ---------------- K1: in_proj GEMM -> xm_raw (B,D,L), zg (B,L,D) ----------------
__global__ __launch_bounds__(256) void k_inproj(const float* __restrict__ x,
                                                const float* __restrict__ w,
                                                float* __restrict__ xm_raw,
                                                float* __restrict__ zg) {
    int b = blockIdx.x >> 6;
    int l0 = (blockIdx.x & 63) << 6;
    int lane = threadIdx.x & 63;
    int jg = threadIdx.x >> 6;
    int jb = __builtin_amdgcn_readfirstlane(jg);
    int l = l0 + lane;
    __shared__ float z_t[128][65];
    const float* xb = x + (size_t)b * CC * LL;
    float xv[64];
#pragma unroll
    for (int c = 0; c < 64; c++) xv[c] = xb[c * LL + l];
    const float* wrow = w + jb * 64 * 64;
    if (jb < 2) {
        float* ob = xm_raw + ((size_t)b * DD + jb * 64) * LL + l0;
        for (int jj = 0; jj < 64; jj++) {
            float acc = 0.f;
#pragma unroll
            for (int c = 0; c < 64; c++) acc = fmaf(xv[c], wrow[jj * 64 + c], acc);
            ob[(size_t)jj * LL + lane] = acc;
        }
    } else {
        int zd0 = (jb - 2) * 64;
        for (int jj = 0; jj < 64; jj++) {
            float acc = 0.f;
#pragma unroll
            for (int c = 0; c < 64; c++) acc = fmaf(xv[c], wrow[jj * 64 + c], acc);
            z_t[zd0 + jj][lane] = acc;
        }
    }
    __syncthreads();
    int d = threadIdx.x & 127, lsub = threadIdx.x >> 7;
    float* zb = zg + ((size_t)b * LL + l0) * DD;
    for (int p = 0; p < 32; p++) {
        int ll = p * 2 + lsub;
        zb[(size_t)ll * DD + d] = z_t[d][ll];
    }
}

// ---------------- K1b: causal depthwise conv1d (k=4) + SiLU -> xmg (B,L,D) ----------------
__global__ __launch_bounds__(256) void k_conv1d(const float* __restrict__ xm_raw,
                                                const float* __restrict__ cw,
                                                const float* __restrict__ cb,
                                                float* __restrict__ xmg) {
    int b = blockIdx.x >> 6;
    int l0 = (blockIdx.x & 63) << 6;
    __shared__ float s[128][69];
    for (int idx = threadIdx.x; idx < 128 * 67; idx += 256) {
        int row = idx / 67, col = idx % 67;
        int l = l0 - 3 + col;
        s[row][col] = (l >= 0) ? xm_raw[((size_t)b * DD + row) * LL + l] : 0.f;
    }
    __syncthreads();
    int d = threadIdx.x & 127, lsub = threadIdx.x >> 7;
    float w0 = cw[d * 4], w1 = cw[d * 4 + 1], w2 = cw[d * 4 + 2], w3 = cw[d * 4 + 3];
    float bb = cb[d];
    float* ob = xmg + ((size_t)b * LL + l0) * DD;
#pragma unroll 4
    for (int i = 0; i < 32; i++) {
        int ll = i * 2 + lsub;
        float v = bb + w0 * s[d][ll] + w1 * s[d][ll + 1] + w2 * s[d][ll + 2] + w3 * s[d][ll + 3];
        ob[(size_t)ll * DD + d] = silu_f(v);
    }
}

// ---------------- K2: x_proj -> Bc2/Cc2 (B,L,16), dtp (B,L,4)  (4 j-groups/wave) ----------------
__global__ __launch_bounds__(256) void k_xproj_bc(const float* __restrict__ xmg,
                                                  const float* __restrict__ xw,
                                                  float* __restrict__ Bc2,
                                                  float* __restrict__ Cc2,
                                                  float* __restrict__ dtpO) {
    int blk = blockIdx.x;                        // 512
    int bl = (blk << 6) + (threadIdx.x & 63);
    int j0 = __builtin_amdgcn_readfirstlane(threadIdx.x >> 6) * 9;
    const float* xr = xmg + (size_t)bl * DD;
    float acc[9];
#pragma unroll
    for (int j = 0; j < 9; j++) acc[j] = 0.f;
    for (int c8 = 0; c8 < 8; c8++) {
        float4 v0 = *(const float4*)(xr + c8 * 16 + 0);
        float4 v1 = *(const float4*)(xr + c8 * 16 + 4);
        float4 v2 = *(const float4*)(xr + c8 * 16 + 8);
        float4 v3 = *(const float4*)(xr + c8 * 16 + 12);
        float xv[16] = {v0.x, v0.y, v0.z, v0.w, v1.x, v1.y, v1.z, v1.w,
                        v2.x, v2.y, v2.z, v2.w, v3.x, v3.y, v3.z, v3.w};
#pragma unroll
        for (int jj = 0; jj < 9; jj++) {
            const float* wr = xw + (j0 + jj) * DD + c8 * 16;
            float a = acc[jj];
#pragma unroll
            for (int j = 0; j < 16; j++) a = fmaf(xv[j], wr[j], a);
            acc[jj] = a;
        }
    }
#pragma unroll
    for (int jj = 0; jj < 9; jj++) {
        int j = j0 + jj;
        if (j < 4)       dtpO[(size_t)bl * 4 + j] = acc[jj];
        else if (j < 20) Bc2[(size_t)bl * 16 + (j - 4)] = acc[jj];
        else             Cc2[(size_t)bl * 16 + (j - 20)] = acc[jj];
    }
}

// ---------------- Scan pass 1 ----------------
__global__ __launch_bounds__(64) void k_s1(const float* __restrict__ xmg,
                                           const float* __restrict__ Bc2,
                                           const float* __restrict__ dtpI,
                                           const float* __restrict__ dtw,
                                           const float* __restrict__ dtb,
                                           const float* __restrict__ A_log,
                                           float* __restrict__ chH,
                                           float* __restrict__ chP) {
    int g = blockIdx.x;
    int ck = g & (NCH - 1);
    int dh = (g >> 7) & 1;
    int b = g >> 8;
    int lane = threadIdx.x;
    int d = dh * 64 + lane;
    float a2[16];
#pragma unroll
    for (int j = 0; j < 4; j++) {
        float4 v = *(const float4*)(A_log + d * 16 + j * 4);
        a2[j * 4 + 0] = -__expf(v.x) * 1.4426950408889634f;
        a2[j * 4 + 1] = -__expf(v.y) * 1.4426950408889634f;
        a2[j * 4 + 2] = -__expf(v.z) * 1.4426950408889634f;
        a2[j * 4 + 3] = -__expf(v.w) * 1.4426950408889634f;
    }
    float4 dw = *(const float4*)(dtw + d * 4);
    float dtbd = dtb[d];
    float h[16];
#pragma unroll
    for (int n = 0; n < 16; n++) h[n] = 0.f;
    float sdt = 0.f;
    size_t bl0 = (size_t)b * LL + ck * CLEN;
    const float* xmp = xmg + bl0 * DD + d;
    const float* Bp = Bc2 + bl0 * 16;
    const float* dpp = dtpI + bl0 * 4;
#pragma unroll 2
    for (int t = 0; t < CLEN; t++) {
        float xmv = xmp[(size_t)t * DD];
        float4 q = *(const float4*)(dpp + t * 4);
        float tp = dtbd + q.x * dw.x + q.y * dw.y + q.z * dw.z + q.w * dw.w;
        float dtv = softplus_f(tp);
        float dx = dtv * xmv;
        float4 B0 = *(const float4*)(Bp + t * 16);
        float4 B1 = *(const float4*)(Bp + t * 16 + 4);
        float4 B2 = *(const float4*)(Bp + t * 16 + 8);
        float4 B3 = *(const float4*)(Bp + t * 16 + 12);
        float Bv[16] = {B0.x, B0.y, B0.z, B0.w, B1.x, B1.y, B1.z, B1.w,
                        B2.x, B2.y, B2.z, B2.w, B3.x, B3.y, B3.z, B3.w};
#pragma unroll
        for (int n = 0; n < 16; n++) {
            float dA = exp2f(dtv * a2[n]);
            h[n] = fmaf(dA, h[n], dx * Bv[n]);
        }
        sdt += dtv;
    }
    size_t cbase = ((size_t)((b * 2 + dh) * NCH + ck)) * 1024 + lane * 16;
#pragma unroll
    for (int j = 0; j < 4; j++) {
        *(float4*)(chH + cbase + j * 4) = make_float4(h[j * 4], h[j * 4 + 1], h[j * 4 + 2], h[j * 4 + 3]);
        *(float4*)(chP + cbase + j * 4) = make_float4(exp2f(a2[j * 4] * sdt), exp2f(a2[j * 4 + 1] * sdt),
                                                      exp2f(a2[j * 4 + 2] * sdt), exp2f(a2[j * 4 + 3] * sdt));
    }
}

// ---------------- Scan pass 2 ----------------
__global__ __launch_bounds__(64) void k_s2(float* __restrict__ chH,
                                           const float* __restrict__ chP) {
    int t = blockIdx.x * 64 + threadIdx.x;   // 0..16383
    int row = t >> 10;
    int q = t & 1023;
    size_t base = (size_t)row * NCH * 1024 + q;
    float H = 0.f;
#pragma unroll 8
    for (int ck = 0; ck < NCH; ck++) {
        size_t a = base + (size_t)ck * 1024;
        float h = chH[a];
        float p = chP[a];
        chH[a] = H;
        H = fmaf(p, H, h);
    }
}

// ---------------- Scan pass 3 ----------------
__global__ __launch_bounds__(64) void k_s3(const float* __restrict__ xmg,
                                           const float* __restrict__ zg,
                                           const float* __restrict__ Bc2,
                                           const float* __restrict__ Cc2,
                                           const float* __restrict__ dtpI,
                                           const float* __restrict__ dtw,
                                           const float* __restrict__ dtb,
                                           const float* __restrict__ A_log,
                                           const float* __restrict__ Dpp,
                                           const float* __restrict__ hinit,
                                           float* __restrict__ Y) {
    int g = blockIdx.x;
    int ck = g & (NCH - 1);
    int dh = (g >> 7) & 1;
    int b = g >> 8;
    int lane = threadIdx.x;
    int d = dh * 64 + lane;
    float a2[16];
#pragma unroll
    for (int j = 0; j < 4; j++) {
        float4 v = *(const float4*)(A_log + d * 16 + j * 4);
        a2[j * 4 + 0] = -__expf(v.x) * 1.4426950408889634f;
        a2[j * 4 + 1] = -__expf(v.y) * 1.4426950408889634f;
        a2[j * 4 + 2] = -__expf(v.z) * 1.4426950408889634f;
        a2[j * 4 + 3] = -__expf(v.w) * 1.4426950408889634f;
    }
    float4 dw = *(const float4*)(dtw + d * 4);
    float dtbd = dtb[d];
    float Dpd = Dpp[d];
    size_t cbase = ((size_t)((b * 2 + dh) * NCH + ck)) * 1024 + lane * 16;
    float h[16];
#pragma unroll
    for (int j = 0; j < 4; j++) {
        float4 v = *(const float4*)(hinit + cbase + j * 4);
        h[j * 4 + 0] = v.x; h[j * 4 + 1] = v.y; h[j * 4 + 2] = v.z; h[j * 4 + 3] = v.w;
    }
    size_t bl0 = (size_t)b * LL + ck * CLEN;
    const float* xmp = xmg + bl0 * DD + d;
    const float* zp = zg + bl0 * DD + d;
    const float* Bp = Bc2 + bl0 * 16;
    const float* Cp = Cc2 + bl0 * 16;
    const float* dpp = dtpI + bl0 * 4;
    float* Yp = Y + bl0 * DD + d;
#pragma unroll 2
    for (int t = 0; t < CLEN; t++) {
        float xmv = xmp[(size_t)t * DD];
        float zv = zp[(size_t)t * DD];
        float4 q = *(const float4*)(dpp + t * 4);
        float tp = dtbd + q.x * dw.x + q.y * dw.y + q.z * dw.z + q.w * dw.w;
        float dtv = softplus_f(tp);
        float dx = dtv * xmv;
        float4 B0 = *(const float4*)(Bp + t * 16);
        float4 B1 = *(const float4*)(Bp + t * 16 + 4);
        float4 B2 = *(const float4*)(Bp + t * 16 + 8);
        float4 B3 = *(const float4*)(Bp + t * 16 + 12);
        float4 C0 = *(const float4*)(Cp + t * 16);
        float4 C1 = *(const float4*)(Cp + t * 16 + 4);
        float4 C2 = *(const float4*)(Cp + t * 16 + 8);
        float4 C3 = *(const float4*)(Cp + t * 16 + 12);
        float Bv[16] = {B0.x, B0.y, B0.z, B0.w, B1.x, B1.y, B1.z, B1.w,
                        B2.x, B2.y, B2.z, B2.w, B3.x, B3.y, B3.z, B3.w};
        float Cv[16] = {C0.x, C0.y, C0.z, C0.w, C1.x, C1.y, C1.z, C1.w,
                        C2.x, C2.y, C2.z, C2.w, C3.x, C3.y, C3.z, C3.w};
        float y0 = 0.f, y1 = 0.f, y2 = 0.f, y3 = 0.f;
#pragma unroll
        for (int n = 0; n < 16; n += 4) {
            float dA0 = exp2f(dtv * a2[n]);
            float dA1 = exp2f(dtv * a2[n + 1]);
            float dA2 = exp2f(dtv * a2[n + 2]);
            float dA3 = exp2f(dtv * a2[n + 3]);
            h[n] = fmaf(dA0, h[n], dx * Bv[n]);
            h[n + 1] = fmaf(dA1, h[n + 1], dx * Bv[n + 1]);
            h[n + 2] = fmaf(dA2, h[n + 2], dx * Bv[n + 2]);
            h[n + 3] = fmaf(dA3, h[n + 3], dx * Bv[n + 3]);
            y0 = fmaf(h[n], Cv[n], y0);
            y1 = fmaf(h[n + 1], Cv[n + 1], y1);
            y2 = fmaf(h[n + 2], Cv[n + 2], y2);
            y3 = fmaf(h[n + 3], Cv[n + 3], y3);
        }
        float yv = (y0 + y1) + (y2 + y3);
        yv = fmaf(xmv, Dpd, yv);
        Yp[(size_t)t * DD] = yv * silu_f(zv);
    }
}

// ---------------- K4: out_proj + PReLU -> img1t bf16 [b][p*64+q][64]  (4 oc-groups/wave) ----------------
__global__ __launch_bounds__(256) void k_outproj(const float* __restrict__ Y,
                                                 const float* __restrict__ wo,
                                                 const float* __restrict__ pre,
                                                 unsigned short* __restrict__ img1t) {
    int blk = blockIdx.x;                        // 512
    int bl = (blk << 6) + (threadIdx.x & 63);
    int oc0 = __builtin_amdgcn_readfirstlane(threadIdx.x >> 6) * 16;
    const float* yr = Y + (size_t)bl * DD;
    float acc[16];
#pragma unroll
    for (int o = 0; o < 16; o++) acc[o] = 0.f;
    for (int c8 = 0; c8 < 8; c8++) {
        float4 v0 = *(const float4*)(yr + c8 * 16 + 0);
        float4 v1 = *(const float4*)(yr + c8 * 16 + 4);
        float4 v2 = *(const float4*)(yr + c8 * 16 + 8);
        float4 v3 = *(const float4*)(yr + c8 * 16 + 12);
        float xv[16] = {v0.x, v0.y, v0.z, v0.w, v1.x, v1.y, v1.z, v1.w,
                        v2.x, v2.y, v2.z, v2.w, v3.x, v3.y, v3.z, v3.w};
#pragma unroll
        for (int o = 0; o < 16; o++) {
            const float* wr = wo + (size_t)(oc0 + o) * DD + c8 * 16;
            float a = acc[o];
#pragma unroll
            for (int j = 0; j < 16; j++) a = fmaf(xv[j], wr[j], a);
            acc[o] = a;
        }
    }
    float pa = pre[0];
    int b = bl >> 12, l = bl & 4095;
    int px = (l & 63) * 64 + (l >> 6);           // (p = l%64, q = l/64)
    unsigned short* dst = img1t + ((size_t)b * 4096 + px) * 64 + oc0;
#pragma unroll
    for (int g8 = 0; g8 < 2; g8++) {
        ushort8v w;
#pragma unroll
        for (int j = 0; j < 8; j++) {
            float v = acc[g8 * 8 + j];
            v = v >= 0.f ? v : pa * v;
            w[j] = f2bf(v);
        }
        *(ushort8v*)(dst + g8 * 8) = w;
    }
}

// ---------------- weight prep: Wk[oc][shift*64+ic] bf16 for both 3x3 convs ----------------
__global__ __launch_bounds__(256) void k_wprep(const float* __restrict__ w1,
                                               const float* __restrict__ w2,
                                               unsigned short* __restrict__ Wk1,
                                               unsigned short* __restrict__ Wk2) {
    int idx = blockIdx.x * 256 + threadIdx.x;
    if (idx >= 2 * 36864) return;
    const float* w = (idx < 36864) ? w1 : w2;
    unsigned short* dst = (idx < 36864) ? Wk1 : Wk2;
    int r = (idx < 36864) ? idx : idx - 36864;
    int oc = r / 576, k = r % 576;
    int shift = k >> 6, ic = k & 63;
    dst[oc * 576 + k] = f2bf(w[(oc * 64 + ic) * 9 + shift]);
}

// ---------------- K5/K6: 3x3 conv via MFMA bf16 + BN + PReLU (+residual) ----------------
template <bool FINAL>
__global__ __launch_bounds__(256) void k_conv3m(const unsigned short* __restrict__ in_t,
                                                const unsigned short* __restrict__ Wk,
                                                const float* __restrict__ bnp,
                                                const float* __restrict__ pre,
                                                unsigned short* __restrict__ out_t,
                                                float* __restrict__ outf) {
    int bid = blockIdx.x;
    int b = bid >> 6;
    int p = bid & 63;
    int tid = threadIdx.x;
    int lane = tid & 63;
    int wv = tid >> 6;
    int oc0 = __builtin_amdgcn_readfirstlane(wv * 16);
    __shared__ unsigned short lds[3 * 66 * 64];

    short8 afrag[18];
    const unsigned short* wrow = Wk + (size_t)(oc0 + (lane & 15)) * 576 + ((lane >> 4) * 8);
#pragma unroll
    for (int s = 0; s < 18; s++) afrag[s] = *(const short8*)(wrow + s * 32);

    const unsigned short* ib = in_t + (size_t)b * 4096 * 64;
    for (int idx = tid; idx < 1584; idx += 256) {
        int pair = idx >> 3, c = idx & 7;
        int di = pair / 66, col = pair % 66;
        int r = p - 1 + di, q = col - 1;
        ushort8v v = {0, 0, 0, 0, 0, 0, 0, 0};
        if (r >= 0 && r < 64 && q >= 0 && q < 64)
            v = *(const ushort8v*)(ib + ((size_t)(r * 64 + q)) * 64 + c * 8);
        *(ushort8v*)(lds + pair * 64 + ((c ^ (col & 7)) * 8)) = v;
    }
    __syncthreads();

    f32x4 acc[4];
#pragma unroll
    for (int n0 = 0; n0 < 4; n0++) acc[n0] = (f32x4){0.f, 0.f, 0.f, 0.f};
#pragma unroll
    for (int s = 0; s < 18; s++) {
        const int shift = s >> 1, h = s & 1;
        const int di = shift / 3, dj = shift % 3;
#pragma unroll
        for (int n0 = 0; n0 < 4; n0++) {
            int col = n0 * 16 + (lane & 15) + dj;
            int off = (di * 66 + col) * 64 + (((h * 4 + (lane >> 4)) ^ (col & 7)) * 8);
            short8 bfrag = *(const short8*)(lds + off);
            acc[n0] = __builtin_amdgcn_mfma_f32_16x16x32_bf16(afrag[s], bfrag, acc[n0], 0, 0, 0);
        }
    }

    int ocb = oc0 + ((lane >> 4) << 2);
    float4 g4 = *(const float4*)(bnp + ocb);
    float4 be4 = *(const float4*)(bnp + 64 + ocb);
    float4 m4 = *(const float4*)(bnp + 128 + ocb);
    float4 v4 = *(const float4*)(bnp + 192 + ocb);
    float sc[4], sh[4];
    sc[0] = g4.x * rsqrtf(v4.x + EPS); sh[0] = be4.x - m4.x * sc[0];
    sc[1] = g4.y * rsqrtf(v4.y + EPS); sh[1] = be4.y - m4.y * sc[1];
    sc[2] = g4.z * rsqrtf(v4.z + EPS); sh[2] = be4.z - m4.z * sc[2];
    sc[3] = g4.w * rsqrtf(v4.w + EPS); sh[3] = be4.w - m4.w * sc[3];
    float pa = pre[0];
#pragma unroll
    for (int n0 = 0; n0 < 4; n0++) {
        int q = n0 * 16 + (lane & 15);
        float vals[4];
#pragma unroll
        for (int r = 0; r < 4; r++) {
            float v = fmaf(acc[n0][r], sc[r], sh[r]);
            vals[r] = v >= 0.f ? v : pa * v;
        }
        if (FINAL) {
#pragma unroll
            for (int r = 0; r < 4; r++) {
                size_t addr = ((size_t)b * 64 + ocb + r) * 4096 + p * 64 + q;
                outf[addr] = vals[r] + outf[addr];
            }
        } else {
            ushort4 u = make_ushort4(f2bf(vals[0]), f2bf(vals[1]), f2bf(vals[2]), f2bf(vals[3]));
            *(ushort4*)(out_t + ((size_t)b * 4096 + p * 64 + q) * 64 + ocb) = u;
        }
    }
}

extern "C" void kernel_launch(void* const* d_in, const int* in_sizes, int n_in,
                              void* d_out, int out_size, void* d_ws, size_t ws_size,
                              hipStream_t stream) {
    const float* x = (const float*)d_in[0];
    const float* in_proj_w = (const float*)d_in[1];
    const float* conv1d_w = (const float*)d_in[2];
    const float* conv1d_b = (const float*)d_in[3];
    const float* x_proj_w = (const float*)d_in[4];
    const float* dt_proj_w = (const float*)d_in[5];
    const float* dt_proj_b = (const float*)d_in[6];
    const float* A_log = (const float*)d_in[7];
    const float* Dp = (const float*)d_in[8];
    const float* out_proj_w = (const float*)d_in[9];
    const float* prelu_ssm = (const float*)d_in[10];
    const float* res_w = (const float*)d_in[11];
    const float* res_bn = (const float*)d_in[12];
    const float* conv1_w = (const float*)d_in[13];
    const float* bn1 = (const float*)d_in[14];
    const float* prelu1 = (const float*)d_in[15];
    const float* conv2_w = (const float*)d_in[16];
    const float* bn2 = (const float*)d_in[17];
    const float* prelu2 = (const float*)d_in[18];
    float* out = (float*)d_out;
    float* ws = (float*)d_ws;

    const size_t S = (size_t)BB * LL * DD;        // 4,194,304
    const size_t HALF = S / 2;                    // 2,097,152
    float* xm_raw = ws;                           // [0,S) dead after conv1d
    float* chH = ws;                              // [0,HALF) live s1..s3
    float* chP = ws + HALF;                       // [HALF,S) live s1..s2
    float* xmg = ws + S;
    float* zg = ws + 2 * S;
    float* Yb = ws + 3 * S;
    float* Bc2 = ws + 4 * S;                      // B*L*16; dead after s3 -> reused for Wk
    float* Cc2 = Bc2 + (size_t)BB * LL * 16;
    float* dtp = Cc2 + (size_t)BB * LL * 16;      // B*L*4
    unsigned short* img1t = (unsigned short*)ws;              // after s3
    unsigned short* img2t = (unsigned short*)(ws + HALF);
    unsigned short* Wk1 = (unsigned short*)Bc2;
    unsigned short* Wk2 = Wk1 + 36864;

    k_res<<<dim3(512), dim3(256), 0, stream>>>(x, res_w, res_bn, out);
    k_inproj<<<dim3(512), dim3(256), 0, stream>>>(x, in_proj_w, xm_raw, zg);
    k_conv1d<<<dim3(512), dim3(256), 0, stream>>>(xm_raw, conv1d_w, conv1d_b, xmg);
    k_xproj_bc<<<dim3(512), dim3(256), 0, stream>>>(xmg, x_proj_w, Bc2, Cc2, dtp);
    k_s1<<<dim3(BB * 2 * NCH), dim3(64), 0, stream>>>(xmg, Bc2, dtp, dt_proj_w, dt_proj_b, A_log, chH, chP);
    k_s2<<<dim3(256), dim3(64), 0, stream>>>(chH, chP);
    k_s3<<<dim3(BB * 2 * NCH), dim3(64), 0, stream>>>(xmg, zg, Bc2, Cc2, dtp, dt_proj_w, dt_proj_b,
                                                      A_log, Dp, chH, Yb);
    k_outproj<<<dim3(512), dim3(256), 0, stream>>>(Yb, out_proj_w, prelu_ssm, img1t);
    k_wprep<<<dim3(288), dim3(256), 0, stream>>>(conv1_w, conv2_w, Wk1, Wk2);
    k_conv3m<false><<<dim3(512), dim3(256), 0, stream>>>(img1t, Wk1, bn1, prelu1, img2t, nullptr);
    k_conv3m<true><<<dim3(512), dim3(256), 0, stream>>>(img2t, Wk2, bn2, prelu2, nullptr, out);
}

// Round 6
// 185.829 us; speedup vs baseline: 3.5865x; 1.3074x over previous
//
#include <hip/hip_runtime.h>
#include <hip/hip_bf16.h>

#define BB 8
#define CC 64
#define LL 4096
#define DD 128
#define NN 16
#define EPS 1e-5f
#define NCH 128
#define CLEN 32

typedef short short8 __attribute__((ext_vector_type(8)));
typedef unsigned short ushort8v __attribute__((ext_vector_type(8)));
typedef float f32x4 __attribute__((ext_vector_type(4)));

__device__ __forceinline__ float silu_f(float v) {
    return v / (1.f + __expf(-v));
}
__device__ __forceinline__ float softplus_f(float t) {
    return fmaxf(t, 0.f) + __logf(1.f + __expf(-fabsf(t)));
}
__device__ __forceinline__ unsigned short f2bf(float f) {
    unsigned int u = __float_as_uint(f);
    u += 0x7fff + ((u >> 16) & 1);
    return (unsigned short)(u >> 16);
}
__device__ __forceinline__ float bf2f(unsigned short u) {
    return __uint_as_float(((unsigned int)u) << 16);
}

// ---------------- K0: residual 1x1 conv + BN -> d_out  (4 oc-groups/wave) ----------------
__global__ __launch_bounds__(256) void k_res(const float* __restrict__ x,
                                             const float* __restrict__ rw,
                                             const float* __restrict__ rbn,
                                             float* __restrict__ out) {
    int blk = blockIdx.x;                       // 512
    int b = blk >> 6;
    int s = ((blk & 63) << 6) + (threadIdx.x & 63);
    int oc0 = __builtin_amdgcn_readfirstlane(threadIdx.x >> 6) * 16;
    const float* xb = x + (size_t)b * CC * LL;
    float xv[64];
#pragma unroll
    for (int ic = 0; ic < 64; ic++) xv[ic] = xb[ic * LL + s];
#pragma unroll
    for (int o = 0; o < 16; o++) {
        int oc = oc0 + o;
        const float* wr = rw + oc * 64;
        float acc = 0.f;
#pragma unroll
        for (int ic = 0; ic < 64; ic++) acc = fmaf(xv[ic], wr[ic], acc);
        float g = rbn[oc], be = rbn[64 + oc], m = rbn[128 + oc], v = rbn[192 + oc];
        float sc = g * rsqrtf(v + EPS);
        float sh = be - m * sc;
        out[((size_t)b * 64 + oc) * LL + s] = fmaf(acc, sc, sh);
    }
}

// ---------------- k_front: in_proj (MFMA) + conv1d + SiLU + x_proj (MFMA) fused ----------------
// outputs: xmg bf16 (B,L,128), zg bf16 (B,L,128), Bc2/Cc2 f32 (B,L,16), dtp f32 (B,L,4)
__global__ __launch_bounds__(256) void k_front(const float* __restrict__ x,
                                               const float* __restrict__ wip,
                                               const float* __restrict__ xw,
                                               const float* __restrict__ cw,
                                               const float* __restrict__ cb,
                                               unsigned short* __restrict__ xmg,
                                               unsigned short* __restrict__ zg,
                                               float* __restrict__ Bc2,
                                               float* __restrict__ Cc2,
                                               float* __restrict__ dtpO) {
    int blk = blockIdx.x;                        // 512 = B * (L/64)
    int b = blk >> 6;
    int l0 = (blk & 63) << 6;
    int tid = threadIdx.x;
    int lane = tid & 63;
    int wv = __builtin_amdgcn_readfirstlane(tid >> 6);
    int l15 = lane & 15, l4g = lane >> 4;

    __shared__ unsigned short xt[80 * 64];       // x tile bf16, swizzled chunks
    __shared__ unsigned short xmf[80 * 132];     // pre-conv xm bf16, padded rows
    __shared__ unsigned short zf[64 * 132];      // z bf16, padded rows
    __shared__ unsigned short xmc[64 * 128];     // post-conv xm bf16, swizzled chunks

    // ---- stage x tile: tokens l = l0-3 .. l0+76 (j=0..79), 64 channels ----
    for (int idx = tid; idx < 5120; idx += 256) {
        int c = idx / 80;
        int j = idx - c * 80;
        int l = l0 - 3 + j;
        float v = (l >= 0 && l < LL) ? x[((size_t)b * CC + c) * LL + l] : 0.f;
        xt[j * 64 + (((c >> 3) ^ (j & 7)) * 8) + (c & 7)] = f2bf(v);
    }

    // ---- A fragments: in_proj rows wv*64 .. wv*64+63 ----
    short8 af[4][2];
#pragma unroll
    for (int m0 = 0; m0 < 4; m0++) {
        const float* wr = wip + (size_t)(wv * 64 + m0 * 16 + l15) * 64 + l4g * 8;
#pragma unroll
        for (int h = 0; h < 2; h++) {
            float4 a0 = *(const float4*)(wr + h * 32);
            float4 a1 = *(const float4*)(wr + h * 32 + 4);
            short8 f;
            f[0] = (short)f2bf(a0.x); f[1] = (short)f2bf(a0.y);
            f[2] = (short)f2bf(a0.z); f[3] = (short)f2bf(a0.w);
            f[4] = (short)f2bf(a1.x); f[5] = (short)f2bf(a1.y);
            f[6] = (short)f2bf(a1.z); f[7] = (short)f2bf(a1.w);
            af[m0][h] = f;
        }
    }
    __syncthreads();

    // ---- in_proj MFMA: M=64 (this wave), N=80 tokens, K=64 ----
    f32x4 acc[4][5];
#pragma unroll
    for (int m0 = 0; m0 < 4; m0++)
#pragma unroll
        for (int n0 = 0; n0 < 5; n0++) acc[m0][n0] = (f32x4){0.f, 0.f, 0.f, 0.f};
#pragma unroll
    for (int n0 = 0; n0 < 5; n0++) {
        int j = n0 * 16 + l15;
#pragma unroll
        for (int h = 0; h < 2; h++) {
            short8 bf = *(const short8*)(xt + j * 64 + (((h * 4 + l4g) ^ (j & 7)) * 8));
#pragma unroll
            for (int m0 = 0; m0 < 4; m0++)
                acc[m0][n0] = __builtin_amdgcn_mfma_f32_16x16x32_bf16(af[m0][h], bf, acc[m0][n0], 0, 0, 0);
        }
    }

    // ---- scatter acc: waves 0,1 -> xmf (pre-conv xm); waves 2,3 -> zf ----
#pragma unroll
    for (int m0 = 0; m0 < 4; m0++)
#pragma unroll
        for (int n0 = 0; n0 < 5; n0++) {
            int j = n0 * 16 + l15;
            int d = (wv & 1) * 64 + m0 * 16 + l4g * 4;
            ushort4 u = make_ushort4(f2bf(acc[m0][n0][0]), f2bf(acc[m0][n0][1]),
                                     f2bf(acc[m0][n0][2]), f2bf(acc[m0][n0][3]));
            if (wv < 2) {
                *(ushort4*)(xmf + j * 132 + d) = u;
            } else {
                int t = j - 3;
                if (t >= 0 && t < 64) *(ushort4*)(zf + t * 132 + d) = u;
            }
        }
    __syncthreads();

    // ---- conv1d (k=4 causal) + SiLU; write xmg global + xmc LDS; copy z out ----
    {
        int d4 = (tid & 31) * 4;
        int tok0 = (tid >> 5) * 8;
        float4 w0 = *(const float4*)(cw + (d4 + 0) * 4);
        float4 w1 = *(const float4*)(cw + (d4 + 1) * 4);
        float4 w2 = *(const float4*)(cw + (d4 + 2) * 4);
        float4 w3 = *(const float4*)(cw + (d4 + 3) * 4);
        float4 cb4 = *(const float4*)(cb + d4);
        size_t gbase = (size_t)b * LL + l0;
        int kc = d4 >> 3;
#pragma unroll
        for (int tt = 0; tt < 8; tt++) {
            int tok = tok0 + tt;
            ushort4 r0 = *(const ushort4*)(xmf + (tok + 0) * 132 + d4);
            ushort4 r1 = *(const ushort4*)(xmf + (tok + 1) * 132 + d4);
            ushort4 r2 = *(const ushort4*)(xmf + (tok + 2) * 132 + d4);
            ushort4 r3 = *(const ushort4*)(xmf + (tok + 3) * 132 + d4);
            float v0 = cb4.x + w0.x * bf2f(r0.x) + w0.y * bf2f(r1.x) + w0.z * bf2f(r2.x) + w0.w * bf2f(r3.x);
            float v1 = cb4.y + w1.x * bf2f(r0.y) + w1.y * bf2f(r1.y) + w1.z * bf2f(r2.y) + w1.w * bf2f(r3.y);
            float v2 = cb4.z + w2.x * bf2f(r0.z) + w2.y * bf2f(r1.z) + w2.z * bf2f(r2.z) + w2.w * bf2f(r3.z);
            float v3 = cb4.w + w3.x * bf2f(r0.w) + w3.y * bf2f(r1.w) + w3.z * bf2f(r2.w) + w3.w * bf2f(r3.w);
            ushort4 o = make_ushort4(f2bf(silu_f(v0)), f2bf(silu_f(v1)), f2bf(silu_f(v2)), f2bf(silu_f(v3)));
            *(ushort4*)(xmg + (gbase + tok) * 128 + d4) = o;
            *(ushort4*)(xmc + tok * 128 + ((kc ^ (tok & 7)) * 8) + (d4 & 4)) = o;
            ushort4 zv = *(const ushort4*)(zf + tok * 132 + d4);
            *(ushort4*)(zg + (gbase + tok) * 128 + d4) = zv;
        }
    }
    __syncthreads();

    // ---- x_proj MFMA: M=48 (36 used), N=16 tokens per wave, K=128 ----
    short8 pa_[3][4];
#pragma unroll
    for (int mt = 0; mt < 3; mt++) {
        int j = mt * 16 + l15;
#pragma unroll
        for (int ks = 0; ks < 4; ks++) {
            short8 f = {0, 0, 0, 0, 0, 0, 0, 0};
            if (j < 36) {
                const float* wr = xw + (size_t)j * 128 + ks * 32 + l4g * 8;
                float4 a0 = *(const float4*)(wr);
                float4 a1 = *(const float4*)(wr + 4);
                f[0] = (short)f2bf(a0.x); f[1] = (short)f2bf(a0.y);
                f[2] = (short)f2bf(a0.z); f[3] = (short)f2bf(a0.w);
                f[4] = (short)f2bf(a1.x); f[5] = (short)f2bf(a1.y);
                f[6] = (short)f2bf(a1.z); f[7] = (short)f2bf(a1.w);
            }
            pa_[mt][ks] = f;
        }
    }
    int t = wv * 16 + l15;
    f32x4 a3[3];
#pragma unroll
    for (int mt = 0; mt < 3; mt++) a3[mt] = (f32x4){0.f, 0.f, 0.f, 0.f};
#pragma unroll
    for (int ks = 0; ks < 4; ks++) {
        short8 bf = *(const short8*)(xmc + t * 128 + (((ks * 4 + l4g) ^ (t & 7)) * 8));
#pragma unroll
        for (int mt = 0; mt < 3; mt++)
            a3[mt] = __builtin_amdgcn_mfma_f32_16x16x32_bf16(pa_[mt][ks], bf, a3[mt], 0, 0, 0);
    }
    size_t bl = (size_t)b * LL + l0 + t;
    float4 o0 = make_float4(a3[0][0], a3[0][1], a3[0][2], a3[0][3]);
    float4 o1 = make_float4(a3[1][0], a3[1][1], a3[1][2], a3[1][3]);
    float4 o2 = make_float4(a3[2][0], a3[2][1], a3[2][2], a3[2][3]);
    if (l4g == 0) {
        *(float4*)(dtpO + bl * 4) = o0;
        *(float4*)(Bc2 + bl * 16 + 12) = o1;
        *(float4*)(Cc2 + bl * 16 + 12) = o2;
    } else {
        *(float4*)(Bc2 + bl * 16 + (l4g - 1) * 4) = o0;
        *(float4*)(Cc2 + bl * 16 + (l4g - 1) * 4) = o1;
    }
}

// ---------------- Scan pass 1 ----------------
__global__ __launch_bounds__(64) void k_s1(const unsigned short* __restrict__ xmg,
                                           const float* __restrict__ Bc2,
                                           const float* __restrict__ dtpI,
                                           const float* __restrict__ dtw,
                                           const float* __restrict__ dtb,
                                           const float* __restrict__ A_log,
                                           float* __restrict__ chH,
                                           float* __restrict__ chP) {
    int g = blockIdx.x;
    int ck = g & (NCH - 1);
    int dh = (g >> 7) & 1;
    int b = g >> 8;
    int lane = threadIdx.x;
    int d = dh * 64 + lane;
    float a2[16];
#pragma unroll
    for (int j = 0; j < 4; j++) {
        float4 v = *(const float4*)(A_log + d * 16 + j * 4);
        a2[j * 4 + 0] = -__expf(v.x) * 1.4426950408889634f;
        a2[j * 4 + 1] = -__expf(v.y) * 1.4426950408889634f;
        a2[j * 4 + 2] = -__expf(v.z) * 1.4426950408889634f;
        a2[j * 4 + 3] = -__expf(v.w) * 1.4426950408889634f;
    }
    float4 dw = *(const float4*)(dtw + d * 4);
    float dtbd = dtb[d];
    float h[16];
#pragma unroll
    for (int n = 0; n < 16; n++) h[n] = 0.f;
    float sdt = 0.f;
    size_t bl0 = (size_t)b * LL + ck * CLEN;
    const unsigned short* xmp = xmg + bl0 * DD + d;
    const float* Bp = Bc2 + bl0 * 16;
    const float* dpp = dtpI + bl0 * 4;
#pragma unroll 2
    for (int t = 0; t < CLEN; t++) {
        float xmv = bf2f(xmp[(size_t)t * DD]);
        float4 q = *(const float4*)(dpp + t * 4);
        float tp = dtbd + q.x * dw.x + q.y * dw.y + q.z * dw.z + q.w * dw.w;
        float dtv = softplus_f(tp);
        float dx = dtv * xmv;
        float4 B0 = *(const float4*)(Bp + t * 16);
        float4 B1 = *(const float4*)(Bp + t * 16 + 4);
        float4 B2 = *(const float4*)(Bp + t * 16 + 8);
        float4 B3 = *(const float4*)(Bp + t * 16 + 12);
        float Bv[16] = {B0.x, B0.y, B0.z, B0.w, B1.x, B1.y, B1.z, B1.w,
                        B2.x, B2.y, B2.z, B2.w, B3.x, B3.y, B3.z, B3.w};
#pragma unroll
        for (int n = 0; n < 16; n++) {
            float dA = exp2f(dtv * a2[n]);
            h[n] = fmaf(dA, h[n], dx * Bv[n]);
        }
        sdt += dtv;
    }
    size_t cbase = ((size_t)((b * 2 + dh) * NCH + ck)) * 1024 + lane * 16;
#pragma unroll
    for (int j = 0; j < 4; j++) {
        *(float4*)(chH + cbase + j * 4) = make_float4(h[j * 4], h[j * 4 + 1], h[j * 4 + 2], h[j * 4 + 3]);
        *(float4*)(chP + cbase + j * 4) = make_float4(exp2f(a2[j * 4] * sdt), exp2f(a2[j * 4 + 1] * sdt),
                                                      exp2f(a2[j * 4 + 2] * sdt), exp2f(a2[j * 4 + 3] * sdt));
    }
}

// ---------------- Scan pass 2 ----------------
__global__ __launch_bounds__(64) void k_s2(float* __restrict__ chH,
                                           const float* __restrict__ chP) {
    int t = blockIdx.x * 64 + threadIdx.x;   // 0..16383
    int row = t >> 10;
    int q = t & 1023;
    size_t base = (size_t)row * NCH * 1024 + q;
    float H = 0.f;
#pragma unroll 8
    for (int ck = 0; ck < NCH; ck++) {
        size_t a = base + (size_t)ck * 1024;
        float h = chH[a];
        float p = chP[a];
        chH[a] = H;
        H = fmaf(p, H, h);
    }
}

// ---------------- Scan pass 3 ----------------
__global__ __launch_bounds__(64) void k_s3(const unsigned short* __restrict__ xmg,
                                           const unsigned short* __restrict__ zg,
                                           const float* __restrict__ Bc2,
                                           const float* __restrict__ Cc2,
                                           const float* __restrict__ dtpI,
                                           const float* __restrict__ dtw,
                                           const float* __restrict__ dtb,
                                           const float* __restrict__ A_log,
                                           const float* __restrict__ Dpp,
                                           const float* __restrict__ hinit,
                                           float* __restrict__ Y) {
    int g = blockIdx.x;
    int ck = g & (NCH - 1);
    int dh = (g >> 7) & 1;
    int b = g >> 8;
    int lane = threadIdx.x;
    int d = dh * 64 + lane;
    float a2[16];
#pragma unroll
    for (int j = 0; j < 4; j++) {
        float4 v = *(const float4*)(A_log + d * 16 + j * 4);
        a2[j * 4 + 0] = -__expf(v.x) * 1.4426950408889634f;
        a2[j * 4 + 1] = -__expf(v.y) * 1.4426950408889634f;
        a2[j * 4 + 2] = -__expf(v.z) * 1.4426950408889634f;
        a2[j * 4 + 3] = -__expf(v.w) * 1.4426950408889634f;
    }
    float4 dw = *(const float4*)(dtw + d * 4);
    float dtbd = dtb[d];
    float Dpd = Dpp[d];
    size_t cbase = ((size_t)((b * 2 + dh) * NCH + ck)) * 1024 + lane * 16;
    float h[16];
#pragma unroll
    for (int j = 0; j < 4; j++) {
        float4 v = *(const float4*)(hinit + cbase + j * 4);
        h[j * 4 + 0] = v.x; h[j * 4 + 1] = v.y; h[j * 4 + 2] = v.z; h[j * 4 + 3] = v.w;
    }
    size_t bl0 = (size_t)b * LL + ck * CLEN;
    const unsigned short* xmp = xmg + bl0 * DD + d;
    const unsigned short* zp = zg + bl0 * DD + d;
    const float* Bp = Bc2 + bl0 * 16;
    const float* Cp = Cc2 + bl0 * 16;
    const float* dpp = dtpI + bl0 * 4;
    float* Yp = Y + bl0 * DD + d;
#pragma unroll 2
    for (int t = 0; t < CLEN; t++) {
        float xmv = bf2f(xmp[(size_t)t * DD]);
        float zv = bf2f(zp[(size_t)t * DD]);
        float4 q = *(const float4*)(dpp + t * 4);
        float tp = dtbd + q.x * dw.x + q.y * dw.y + q.z * dw.z + q.w * dw.w;
        float dtv = softplus_f(tp);
        float dx = dtv * xmv;
        float4 B0 = *(const float4*)(Bp + t * 16);
        float4 B1 = *(const float4*)(Bp + t * 16 + 4);
        float4 B2 = *(const float4*)(Bp + t * 16 + 8);
        float4 B3 = *(const float4*)(Bp + t * 16 + 12);
        float4 C0 = *(const float4*)(Cp + t * 16);
        float4 C1 = *(const float4*)(Cp + t * 16 + 4);
        float4 C2 = *(const float4*)(Cp + t * 16 + 8);
        float4 C3 = *(const float4*)(Cp + t * 16 + 12);
        float Bv[16] = {B0.x, B0.y, B0.z, B0.w, B1.x, B1.y, B1.z, B1.w,
                        B2.x, B2.y, B2.z, B2.w, B3.x, B3.y, B3.z, B3.w};
        float Cv[16] = {C0.x, C0.y, C0.z, C0.w, C1.x, C1.y, C1.z, C1.w,
                        C2.x, C2.y, C2.z, C2.w, C3.x, C3.y, C3.z, C3.w};
        float y0 = 0.f, y1 = 0.f, y2 = 0.f, y3 = 0.f;
#pragma unroll
        for (int n = 0; n < 16; n += 4) {
            float dA0 = exp2f(dtv * a2[n]);
            float dA1 = exp2f(dtv * a2[n + 1]);
            float dA2 = exp2f(dtv * a2[n + 2]);
            float dA3 = exp2f(dtv * a2[n + 3]);
            h[n] = fmaf(dA0, h[n], dx * Bv[n]);
            h[n + 1] = fmaf(dA1, h[n + 1], dx * Bv[n + 1]);
            h[n + 2] = fmaf(dA2, h[n + 2], dx * Bv[n + 2]);
            h[n + 3] = fmaf(dA3, h[n + 3], dx * Bv[n + 3]);
            y0 = fmaf(h[n], Cv[n], y0);
            y1 = fmaf(h[n + 1], Cv[n + 1], y1);
            y2 = fmaf(h[n + 2], Cv[n + 2], y2);
            y3 = fmaf(h[n + 3], Cv[n + 3], y3);
        }
        float yv = (y0 + y1) + (y2 + y3);
        yv = fmaf(xmv, Dpd, yv);
        Yp[(size_t)t * DD] = yv * silu_f(zv);
    }
}

// ---------------- K4: out_proj + PReLU -> img1t bf16 [b][p*64+q][64]  (4 oc-groups/wave) ----------------
__global__ __launch_bounds__(256) void k_outproj(const float* __restrict__ Y,
                                                 const float* __restrict__ wo,
                                                 const float* __restrict__ pre,
                                                 unsigned short* __restrict__ img1t) {
    int blk = blockIdx.x;                        // 512
    int bl = (blk << 6) + (threadIdx.x & 63);
    int oc0 = __builtin_amdgcn_readfirstlane(threadIdx.x >> 6) * 16;
    const float* yr = Y + (size_t)bl * DD;
    float acc[16];
#pragma unroll
    for (int o = 0; o < 16; o++) acc[o] = 0.f;
    for (int c8 = 0; c8 < 8; c8++) {
        float4 v0 = *(const float4*)(yr + c8 * 16 + 0);
        float4 v1 = *(const float4*)(yr + c8 * 16 + 4);
        float4 v2 = *(const float4*)(yr + c8 * 16 + 8);
        float4 v3 = *(const float4*)(yr + c8 * 16 + 12);
        float xv[16] = {v0.x, v0.y, v0.z, v0.w, v1.x, v1.y, v1.z, v1.w,
                        v2.x, v2.y, v2.z, v2.w, v3.x, v3.y, v3.z, v3.w};
#pragma unroll
        for (int o = 0; o < 16; o++) {
            const float* wr = wo + (size_t)(oc0 + o) * DD + c8 * 16;
            float a = acc[o];
#pragma unroll
            for (int j = 0; j < 16; j++) a = fmaf(xv[j], wr[j], a);
            acc[o] = a;
        }
    }
    float pa = pre[0];
    int b = bl >> 12, l = bl & 4095;
    int px = (l & 63) * 64 + (l >> 6);           // (p = l%64, q = l/64)
    unsigned short* dst = img1t + ((size_t)b * 4096 + px) * 64 + oc0;
#pragma unroll
    for (int g8 = 0; g8 < 2; g8++) {
        ushort8v w;
#pragma unroll
        for (int j = 0; j < 8; j++) {
            float v = acc[g8 * 8 + j];
            v = v >= 0.f ? v : pa * v;
            w[j] = f2bf(v);
        }
        *(ushort8v*)(dst + g8 * 8) = w;
    }
}

// ---------------- weight prep: Wk[oc][shift*64+ic] bf16 for both 3x3 convs ----------------
__global__ __launch_bounds__(256) void k_wprep(const float* __restrict__ w1,
                                               const float* __restrict__ w2,
                                               unsigned short* __restrict__ Wk1,
                                               unsigned short* __restrict__ Wk2) {
    int idx = blockIdx.x * 256 + threadIdx.x;
    if (idx >= 2 * 36864) return;
    const float* w = (idx < 36864) ? w1 : w2;
    unsigned short* dst = (idx < 36864) ? Wk1 : Wk2;
    int r = (idx < 36864) ? idx : idx - 36864;
    int oc = r / 576, k = r % 576;
    int shift = k >> 6, ic = k & 63;
    dst[oc * 576 + k] = f2bf(w[(oc * 64 + ic) * 9 + shift]);
}

// ---------------- K5/K6: 3x3 conv via MFMA bf16 + BN + PReLU (+residual) ----------------
template <bool FINAL>
__global__ __launch_bounds__(256) void k_conv3m(const unsigned short* __restrict__ in_t,
                                                const unsigned short* __restrict__ Wk,
                                                const float* __restrict__ bnp,
                                                const float* __restrict__ pre,
                                                unsigned short* __restrict__ out_t,
                                                float* __restrict__ outf) {
    int bid = blockIdx.x;
    int b = bid >> 6;
    int p = bid & 63;
    int tid = threadIdx.x;
    int lane = tid & 63;
    int wv = tid >> 6;
    int oc0 = __builtin_amdgcn_readfirstlane(wv * 16);
    __shared__ unsigned short lds[3 * 66 * 64];

    short8 afrag[18];
    const unsigned short* wrow = Wk + (size_t)(oc0 + (lane & 15)) * 576 + ((lane >> 4) * 8);
#pragma unroll
    for (int s = 0; s < 18; s++) afrag[s] = *(const short8*)(wrow + s * 32);

    const unsigned short* ib = in_t + (size_t)b * 4096 * 64;
    for (int idx = tid; idx < 1584; idx += 256) {
        int pair = idx >> 3, c = idx & 7;
        int di = pair / 66, col = pair % 66;
        int r = p - 1 + di, q = col - 1;
        ushort8v v = {0, 0, 0, 0, 0, 0, 0, 0};
        if (r >= 0 && r < 64 && q >= 0 && q < 64)
            v = *(const ushort8v*)(ib + ((size_t)(r * 64 + q)) * 64 + c * 8);
        *(ushort8v*)(lds + pair * 64 + ((c ^ (col & 7)) * 8)) = v;
    }
    __syncthreads();

    f32x4 acc[4];
#pragma unroll
    for (int n0 = 0; n0 < 4; n0++) acc[n0] = (f32x4){0.f, 0.f, 0.f, 0.f};
#pragma unroll
    for (int s = 0; s < 18; s++) {
        const int shift = s >> 1, h = s & 1;
        const int di = shift / 3, dj = shift % 3;
#pragma unroll
        for (int n0 = 0; n0 < 4; n0++) {
            int col = n0 * 16 + (lane & 15) + dj;
            int off = (di * 66 + col) * 64 + (((h * 4 + (lane >> 4)) ^ (col & 7)) * 8);
            short8 bfrag = *(const short8*)(lds + off);
            acc[n0] = __builtin_amdgcn_mfma_f32_16x16x32_bf16(afrag[s], bfrag, acc[n0], 0, 0, 0);
        }
    }

    int ocb = oc0 + ((lane >> 4) << 2);
    float4 g4 = *(const float4*)(bnp + ocb);
    float4 be4 = *(const float4*)(bnp + 64 + ocb);
    float4 m4 = *(const float4*)(bnp + 128 + ocb);
    float4 v4 = *(const float4*)(bnp + 192 + ocb);
    float sc[4], sh[4];
    sc[0] = g4.x * rsqrtf(v4.x + EPS); sh[0] = be4.x - m4.x * sc[0];
    sc[1] = g4.y * rsqrtf(v4.y + EPS); sh[1] = be4.y - m4.y * sc[1];
    sc[2] = g4.z * rsqrtf(v4.z + EPS); sh[2] = be4.z - m4.z * sc[2];
    sc[3] = g4.w * rsqrtf(v4.w + EPS); sh[3] = be4.w - m4.w * sc[3];
    float pa = pre[0];
#pragma unroll
    for (int n0 = 0; n0 < 4; n0++) {
        int q = n0 * 16 + (lane & 15);
        float vals[4];
#pragma unroll
        for (int r = 0; r < 4; r++) {
            float v = fmaf(acc[n0][r], sc[r], sh[r]);
            vals[r] = v >= 0.f ? v : pa * v;
        }
        if (FINAL) {
#pragma unroll
            for (int r = 0; r < 4; r++) {
                size_t addr = ((size_t)b * 64 + ocb + r) * 4096 + p * 64 + q;
                outf[addr] = vals[r] + outf[addr];
            }
        } else {
            ushort4 u = make_ushort4(f2bf(vals[0]), f2bf(vals[1]), f2bf(vals[2]), f2bf(vals[3]));
            *(ushort4*)(out_t + ((size_t)b * 4096 + p * 64 + q) * 64 + ocb) = u;
        }
    }
}

extern "C" void kernel_launch(void* const* d_in, const int* in_sizes, int n_in,
                              void* d_out, int out_size, void* d_ws, size_t ws_size,
                              hipStream_t stream) {
    const float* x = (const float*)d_in[0];
    const float* in_proj_w = (const float*)d_in[1];
    const float* conv1d_w = (const float*)d_in[2];
    const float* conv1d_b = (const float*)d_in[3];
    const float* x_proj_w = (const float*)d_in[4];
    const float* dt_proj_w = (const float*)d_in[5];
    const float* dt_proj_b = (const float*)d_in[6];
    const float* A_log = (const float*)d_in[7];
    const float* Dp = (const float*)d_in[8];
    const float* out_proj_w = (const float*)d_in[9];
    const float* prelu_ssm = (const float*)d_in[10];
    const float* res_w = (const float*)d_in[11];
    const float* res_bn = (const float*)d_in[12];
    const float* conv1_w = (const float*)d_in[13];
    const float* bn1 = (const float*)d_in[14];
    const float* prelu1 = (const float*)d_in[15];
    const float* conv2_w = (const float*)d_in[16];
    const float* bn2 = (const float*)d_in[17];
    const float* prelu2 = (const float*)d_in[18];
    float* out = (float*)d_out;
    float* ws = (float*)d_ws;

    const size_t S = (size_t)BB * LL * DD;        // 4,194,304
    const size_t HALF = S / 2;
    float* chH = ws;                              // [0,HALF) live s1..s3
    float* chP = ws + HALF;                       // [HALF,S) live s1..s2
    unsigned short* xmg = (unsigned short*)(ws + S);       // bf16 (B,L,128)
    unsigned short* zg = (unsigned short*)(ws + 2 * S);    // bf16 (B,L,128)
    float* Yb = ws + 3 * S;                       // f32 (B,L,128)
    float* Bc2 = ws + 4 * S;
    float* Cc2 = Bc2 + (size_t)BB * LL * 16;
    float* dtp = Cc2 + (size_t)BB * LL * 16;
    unsigned short* img1t = (unsigned short*)ws;           // over chH, after s3
    unsigned short* img2t = (unsigned short*)(ws + HALF);  // over chP, after s2
    unsigned short* Wk1 = (unsigned short*)Bc2;            // over Bc2, after s3
    unsigned short* Wk2 = Wk1 + 36864;

    k_res<<<dim3(512), dim3(256), 0, stream>>>(x, res_w, res_bn, out);
    k_front<<<dim3(512), dim3(256), 0, stream>>>(x, in_proj_w, x_proj_w, conv1d_w, conv1d_b,
                                                 xmg, zg, Bc2, Cc2, dtp);
    k_s1<<<dim3(BB * 2 * NCH), dim3(64), 0, stream>>>(xmg, Bc2, dtp, dt_proj_w, dt_proj_b, A_log, chH, chP);
    k_s2<<<dim3(256), dim3(64), 0, stream>>>(chH, chP);
    k_s3<<<dim3(BB * 2 * NCH), dim3(64), 0, stream>>>(xmg, zg, Bc2, Cc2, dtp, dt_proj_w, dt_proj_b,
                                                      A_log, Dp, chH, Yb);
    k_outproj<<<dim3(512), dim3(256), 0, stream>>>(Yb, out_proj_w, prelu_ssm, img1t);
    k_wprep<<<dim3(288), dim3(256), 0, stream>>>(conv1_w, conv2_w, Wk1, Wk2);
    k_conv3m<false><<<dim3(512), dim3(256), 0, stream>>>(img1t, Wk1, bn1, prelu1, img2t, nullptr);
    k_conv3m<true><<<dim3(512), dim3(256), 0, stream>>>(img2t, Wk2, bn2, prelu2, nullptr, out);
}